// Round 1
// baseline (26243.201 us; speedup 1.0000x reference)
//
#include <hip/hip_runtime.h>
#include <cstdint>

#define N_NODES 100000
#define N_EDGES 1600000
#define F_IN 128
#define HID 16
#define HEADS 4
#define OUTC 40
#define NEG_SLOPE 0.2f
#define BN_EPS 1e-5f

static inline int cdiv(int a, int b){ return (a + b - 1) / b; }

// ---- order-preserving float<->uint encoding for atomicMax on floats ----
__device__ __forceinline__ unsigned fenc(float f){
  unsigned u = __float_as_uint(f);
  return (u & 0x80000000u) ? ~u : (u | 0x80000000u);
}
__device__ __forceinline__ float fdec(unsigned u){
  unsigned b = (u & 0x80000000u) ? (u & 0x7FFFFFFFu) : ~u;
  return __uint_as_float(b);
}
// encoded value of -inf
#define ENC_NEG_INF 0x007FFFFFu

__global__ void fill_f32(float* p, float v, int n){
  int i = blockIdx.x * blockDim.x + threadIdx.x;
  if (i < n) p[i] = v;
}
__global__ void fill_u32(unsigned* p, unsigned v, int n){
  int i = blockIdx.x * blockDim.x + threadIdx.x;
  if (i < n) p[i] = v;
}

// C[n,m] = sum_k A[n,k] * W[k,m] (+ bias[m]); W staged in LDS (K*M*4 bytes dyn-shared)
__global__ void gemm_kernel(const float* __restrict__ A, const float* __restrict__ W,
                            const float* __restrict__ bias, float* __restrict__ C,
                            int n, int K, int M){
  extern __shared__ float wsh[];
  for (int i = threadIdx.x; i < K * M; i += blockDim.x) wsh[i] = W[i];
  __syncthreads();
  int idx = blockIdx.x * blockDim.x + threadIdx.x;
  int total = n * M;
  if (idx >= total) return;
  int nn = idx / M;
  int m = idx - nn * M;
  const float* a = A + nn * K;
  float acc = bias ? bias[m] : 0.f;
  for (int k = 0; k < K; ++k) acc += a[k] * wsh[k * M + m];
  C[idx] = acc;
}

// el[n,h] = sum_d featl[n,h,d]*al[h,d]; er likewise
__global__ void elr_kernel(const float* __restrict__ featl,
                           const float* __restrict__ al, const float* __restrict__ ar,
                           float* __restrict__ el, float* __restrict__ er,
                           int n, int D){
  int idx = blockIdx.x * blockDim.x + threadIdx.x;
  if (idx >= n * HEADS) return;
  int h = idx & (HEADS - 1);
  const float* f = featl + (idx >> 2) * (HEADS * D) + h * D;
  float sl = 0.f, sr = 0.f;
  for (int d = 0; d < D; ++d){
    float v = f[d];
    sl += v * al[h * D + d];
    sr += v * ar[h * D + d];
  }
  el[idx] = sl;
  er[idx] = sr;
}

// agg = 2*h + b  (layer 1: identity res_fc + outer residual, fused)
__global__ void residual2_kernel(const float* __restrict__ hh, const float* __restrict__ b,
                                 float* __restrict__ agg, int n, int F){
  int idx = blockIdx.x * blockDim.x + threadIdx.x;
  if (idx >= n * F) return;
  int f = idx % F;
  agg[idx] = 2.f * hh[idx] + b[f];
}

__device__ __forceinline__ float edge_e(const int* src, const int* dst,
                                        const float* el, const float* er,
                                        int ed, int h, int& s, int& d){
  s = src[ed]; d = dst[ed];
  float x = el[s * HEADS + h] + er[d * HEADS + h];
  return x >= 0.f ? x : NEG_SLOPE * x;
}

__global__ void edge_max_kernel(const int* __restrict__ src, const int* __restrict__ dst,
                                const float* __restrict__ el, const float* __restrict__ er,
                                unsigned* __restrict__ menc, int e){
  int idx = blockIdx.x * blockDim.x + threadIdx.x;
  if (idx >= e * HEADS) return;
  int ed = idx >> 2, h = idx & 3, s, d;
  float x = edge_e(src, dst, el, er, ed, h, s, d);
  atomicMax(&menc[d * HEADS + h], fenc(x));
}

__global__ void edge_sum_kernel(const int* __restrict__ src, const int* __restrict__ dst,
                                const float* __restrict__ el, const float* __restrict__ er,
                                const unsigned* __restrict__ menc, float* __restrict__ denom,
                                int e){
  int idx = blockIdx.x * blockDim.x + threadIdx.x;
  if (idx >= e * HEADS) return;
  int ed = idx >> 2, h = idx & 3, s, d;
  float x = edge_e(src, dst, el, er, ed, h, s, d);
  float m = fdec(menc[d * HEADS + h]);
  atomicAdd(&denom[d * HEADS + h], expf(x - m));
}

__global__ void edge_agg_kernel(const int* __restrict__ src, const int* __restrict__ dst,
                                const float* __restrict__ el, const float* __restrict__ er,
                                const unsigned* __restrict__ menc, const float* __restrict__ denom,
                                const float* __restrict__ featl, float* __restrict__ out,
                                int e, int D){
  int idx = blockIdx.x * blockDim.x + threadIdx.x;
  if (idx >= e * HEADS) return;
  int ed = idx >> 2, h = idx & 3, s, d;
  float x = edge_e(src, dst, el, er, ed, h, s, d);
  float m = fdec(menc[d * HEADS + h]);
  float dn = denom[d * HEADS + h];
  dn = dn > 1e-16f ? dn : 1e-16f;
  float alpha = expf(x - m) / dn;
  int F = HEADS * D;
  const float4* fs = (const float4*)(featl + s * F + h * D);
  float* od = out + d * F + h * D;
  for (int q = 0; q < D / 4; ++q){
    float4 v = fs[q];
    atomicAdd(od + q * 4 + 0, alpha * v.x);
    atomicAdd(od + q * 4 + 1, alpha * v.y);
    atomicAdd(od + q * 4 + 2, alpha * v.z);
    atomicAdd(od + q * 4 + 3, alpha * v.w);
  }
}

// BN stats over N rows of 64 features. blockDim=256 (4 row-groups x 64 features).
__global__ void bn_stats_kernel(const float* __restrict__ x, float* __restrict__ sums, int n){
  __shared__ float s[512];
  int tid = threadIdx.x;
  int f = tid & 63, g = tid >> 6;
  float sm = 0.f, sq = 0.f;
  for (int r = blockIdx.x * 4 + g; r < n; r += gridDim.x * 4){
    float v = x[r * 64 + f];
    sm += v; sq += v * v;
  }
  s[tid] = sm; s[256 + tid] = sq;
  __syncthreads();
  if (g == 0){
    float a = s[f] + s[64 + f] + s[128 + f] + s[192 + f];
    float b = s[256 + f] + s[320 + f] + s[384 + f] + s[448 + f];
    atomicAdd(&sums[f], a);
    atomicAdd(&sums[64 + f], b);
  }
}

// stats layout: [sum(64), sumsq(64), mu(64), invstd(64)]
__global__ void bn_finalize_kernel(float* __restrict__ stats, int n){
  int f = threadIdx.x;
  if (f < 64){
    float mu = stats[f] / n;
    float var = stats[64 + f] / n - mu * mu;
    stats[128 + f] = mu;
    stats[192 + f] = rsqrtf(var + BN_EPS);
  }
}

__global__ void bn_apply_kernel(const float* __restrict__ x, const float* __restrict__ stats,
                                const float* __restrict__ gamma, const float* __restrict__ beta,
                                float* __restrict__ y, int n){
  int idx = blockIdx.x * blockDim.x + threadIdx.x;
  if (idx >= n * 64) return;
  int f = idx & 63;
  float v = (x[idx] - stats[128 + f]) * stats[192 + f] * gamma[f] + beta[f];
  y[idx] = v > 0.f ? v : 0.f;
}

extern "C" void kernel_launch(void* const* d_in, const int* in_sizes, int n_in,
                              void* d_out, int out_size, void* d_ws, size_t ws_size,
                              hipStream_t stream){
  const float* feat  = (const float*)d_in[0];
  const int*   src   = (const int*)d_in[1];
  const int*   dst   = (const int*)d_in[2];
  const float* W0    = (const float*)d_in[3];
  const float* al0   = (const float*)d_in[4];
  const float* ar0   = (const float*)d_in[5];
  const float* b0    = (const float*)d_in[6];
  const float* resW0 = (const float*)d_in[7];
  const float* g0    = (const float*)d_in[8];
  const float* be0   = (const float*)d_in[9];
  const float* W1    = (const float*)d_in[10];
  const float* al1   = (const float*)d_in[11];
  const float* ar1   = (const float*)d_in[12];
  const float* b1    = (const float*)d_in[13];
  const float* g1    = (const float*)d_in[14];
  const float* be1   = (const float*)d_in[15];
  const float* W2    = (const float*)d_in[16];
  const float* al2   = (const float*)d_in[17];
  const float* ar2   = (const float*)d_in[18];
  const float* b2    = (const float*)d_in[19];
  const float* resW2 = (const float*)d_in[20];
  float* out = (float*)d_out;

  float*    featl = (float*)d_ws;                 // N*160
  float*    agg   = featl + N_NODES * 160;        // N*64
  float*    h     = agg   + N_NODES * 64;         // N*64
  float*    el    = h     + N_NODES * 64;         // N*4
  float*    er    = el    + N_NODES * 4;          // N*4
  unsigned* menc  = (unsigned*)(er + N_NODES * 4);// N*4
  float*    denom = (float*)(menc + N_NODES * 4); // N*4
  float*    stats = denom + N_NODES * 4;          // 256

  const int B = 256;
  const int gNH  = cdiv(N_NODES * HEADS, B);
  const int gEH  = cdiv(N_EDGES * HEADS, B);
  const int g64  = cdiv(N_NODES * 64, B);
  const int g160 = cdiv(N_NODES * 160, B);

  // ================= layer 0 =================
  gemm_kernel<<<g64, B, F_IN * 64 * 4, stream>>>(feat, W0, nullptr, featl, N_NODES, F_IN, 64);
  elr_kernel<<<gNH, B, 0, stream>>>(featl, al0, ar0, el, er, N_NODES, HID);
  gemm_kernel<<<g64, B, F_IN * 64 * 4, stream>>>(feat, resW0, b0, agg, N_NODES, F_IN, 64);
  fill_u32<<<gNH, B, 0, stream>>>(menc, ENC_NEG_INF, N_NODES * HEADS);
  fill_f32<<<gNH, B, 0, stream>>>(denom, 0.f, N_NODES * HEADS);
  edge_max_kernel<<<gEH, B, 0, stream>>>(src, dst, el, er, menc, N_EDGES);
  edge_sum_kernel<<<gEH, B, 0, stream>>>(src, dst, el, er, menc, denom, N_EDGES);
  edge_agg_kernel<<<gEH, B, 0, stream>>>(src, dst, el, er, menc, denom, featl, agg, N_EDGES, HID);
  fill_f32<<<1, 128, 0, stream>>>(stats, 0.f, 128);
  bn_stats_kernel<<<512, 256, 0, stream>>>(agg, stats, N_NODES);
  bn_finalize_kernel<<<1, 64, 0, stream>>>(stats, N_NODES);
  bn_apply_kernel<<<g64, B, 0, stream>>>(agg, stats, g0, be0, h, N_NODES);

  // ================= layer 1 =================
  gemm_kernel<<<g64, B, 64 * 64 * 4, stream>>>(h, W1, nullptr, featl, N_NODES, 64, 64);
  elr_kernel<<<gNH, B, 0, stream>>>(featl, al1, ar1, el, er, N_NODES, HID);
  residual2_kernel<<<g64, B, 0, stream>>>(h, b1, agg, N_NODES, 64);
  fill_u32<<<gNH, B, 0, stream>>>(menc, ENC_NEG_INF, N_NODES * HEADS);
  fill_f32<<<gNH, B, 0, stream>>>(denom, 0.f, N_NODES * HEADS);
  edge_max_kernel<<<gEH, B, 0, stream>>>(src, dst, el, er, menc, N_EDGES);
  edge_sum_kernel<<<gEH, B, 0, stream>>>(src, dst, el, er, menc, denom, N_EDGES);
  edge_agg_kernel<<<gEH, B, 0, stream>>>(src, dst, el, er, menc, denom, featl, agg, N_EDGES, HID);
  fill_f32<<<1, 128, 0, stream>>>(stats, 0.f, 128);
  bn_stats_kernel<<<512, 256, 0, stream>>>(agg, stats, N_NODES);
  bn_finalize_kernel<<<1, 64, 0, stream>>>(stats, N_NODES);
  bn_apply_kernel<<<g64, B, 0, stream>>>(agg, stats, g1, be1, h, N_NODES);

  // ================= layer 2 =================
  gemm_kernel<<<g160, B, 64 * 160 * 4, stream>>>(h, W2, nullptr, featl, N_NODES, 64, 160);
  elr_kernel<<<gNH, B, 0, stream>>>(featl, al2, ar2, el, er, N_NODES, OUTC);
  gemm_kernel<<<g160, B, 64 * 160 * 4, stream>>>(h, resW2, b2, out, N_NODES, 64, 160);
  fill_u32<<<gNH, B, 0, stream>>>(menc, ENC_NEG_INF, N_NODES * HEADS);
  fill_f32<<<gNH, B, 0, stream>>>(denom, 0.f, N_NODES * HEADS);
  edge_max_kernel<<<gEH, B, 0, stream>>>(src, dst, el, er, menc, N_EDGES);
  edge_sum_kernel<<<gEH, B, 0, stream>>>(src, dst, el, er, menc, denom, N_EDGES);
  edge_agg_kernel<<<gEH, B, 0, stream>>>(src, dst, el, er, menc, denom, featl, out, N_EDGES, OUTC);
}

// Round 2
// 2730.479 us; speedup vs baseline: 9.6112x; 9.6112x over previous
//
#include <hip/hip_runtime.h>
#include <cstdint>

#define N_NODES 100000
#define N_EDGES 1600000
#define F_IN 128
#define HID 16
#define HEADS 4
#define OUTC 40
#define NEG_SLOPE 0.2f
#define BN_EPS 1e-5f

static inline int cdiv(int a, int b){ return (a + b - 1) / b; }

__global__ void fill_f32(float* p, float v, int n){
  int i = blockIdx.x * blockDim.x + threadIdx.x;
  if (i < n) p[i] = v;
}
__global__ void fill_i32(int* p, int v, int n){
  int i = blockIdx.x * blockDim.x + threadIdx.x;
  if (i < n) p[i] = v;
}

// C[n,m] = sum_k A[n,k] * W[k,m] (+ bias[m]); W staged in LDS
__global__ void gemm_kernel(const float* __restrict__ A, const float* __restrict__ W,
                            const float* __restrict__ bias, float* __restrict__ C,
                            int n, int K, int M){
  extern __shared__ float wsh[];
  for (int i = threadIdx.x; i < K * M; i += blockDim.x) wsh[i] = W[i];
  __syncthreads();
  int idx = blockIdx.x * blockDim.x + threadIdx.x;
  int total = n * M;
  if (idx >= total) return;
  int nn = idx / M;
  int m = idx - nn * M;
  const float* a = A + nn * K;
  float acc = bias ? bias[m] : 0.f;
  for (int k = 0; k < K; ++k) acc += a[k] * wsh[k * M + m];
  C[idx] = acc;
}

// el[n,h] = sum_d featl[n,h,d]*al[h,d]; er likewise
__global__ void elr_kernel(const float* __restrict__ featl,
                           const float* __restrict__ al, const float* __restrict__ ar,
                           float* __restrict__ el, float* __restrict__ er,
                           int n, int D){
  int idx = blockIdx.x * blockDim.x + threadIdx.x;
  if (idx >= n * HEADS) return;
  int h = idx & (HEADS - 1);
  const float* f = featl + (idx >> 2) * (HEADS * D) + h * D;
  float sl = 0.f, sr = 0.f;
  for (int d = 0; d < D; ++d){
    float v = f[d];
    sl += v * al[h * D + d];
    sr += v * ar[h * D + d];
  }
  el[idx] = sl;
  er[idx] = sr;
}

// h = 2*h + b  (layer 1: identity res_fc + outer residual, fused; in-place)
__global__ void residual2_kernel(float* __restrict__ hh, const float* __restrict__ b, int n, int F){
  int idx = blockIdx.x * blockDim.x + threadIdx.x;
  if (idx >= n * F) return;
  int f = idx % F;
  hh[idx] = 2.f * hh[idx] + b[f];
}

// ---------------- CSR build ----------------
__global__ void hist_kernel(const int* __restrict__ dst, int* __restrict__ deg){
  int i = blockIdx.x * blockDim.x + threadIdx.x;
  if (i < N_EDGES) atomicAdd(&deg[dst[i]], 1);
}

// single-block scan of deg[0..N) -> rowptr[0..N], cursor[0..N)
__global__ void scan_kernel(const int* __restrict__ deg, int* __restrict__ rowptr,
                            int* __restrict__ cursor){
  __shared__ int part[1024];
  const int T = 1024;
  const int CH = (N_NODES + T - 1) / T;
  int t = threadIdx.x;
  int lo = t * CH, hi = min(lo + CH, N_NODES);
  int s = 0;
  for (int j = lo; j < hi; ++j) s += deg[j];
  part[t] = s;
  __syncthreads();
  for (int off = 1; off < T; off <<= 1){
    int v = part[t];
    int u = (t >= off) ? part[t - off] : 0;
    __syncthreads();
    part[t] = v + u;
    __syncthreads();
  }
  int run = (t > 0) ? part[t - 1] : 0;
  for (int j = lo; j < hi; ++j){
    rowptr[j] = run;
    cursor[j] = run;
    run += deg[j];
  }
  if (t == T - 1) rowptr[N_NODES] = N_EDGES;
}

__global__ void scatter_kernel(const int* __restrict__ src, const int* __restrict__ dst,
                               int* __restrict__ cursor, int* __restrict__ csr_src){
  int i = blockIdx.x * blockDim.x + threadIdx.x;
  if (i >= N_EDGES) return;
  int d = dst[i];
  int pos = atomicAdd(&cursor[d], 1);
  csr_src[pos] = src[i];
}

// ---------------- per-node softmax + aggregation (gather, no atomics) ----------------
__device__ __forceinline__ float leaky(float x){ return x >= 0.f ? x : NEG_SLOPE * x; }
__device__ __forceinline__ float sel4(float4 v, int h){
  float r = v.x;
  r = (h == 1) ? v.y : r;
  r = (h == 2) ? v.z : r;
  r = (h == 3) ? v.w : r;
  return r;
}

// one wave per destination node; io holds the residual init and receives the result
template<int D>
__global__ __launch_bounds__(256) void node_agg_kernel(
    const int* __restrict__ rowptr, const int* __restrict__ csr_src,
    const float* __restrict__ el, const float* __restrict__ er,
    const float* __restrict__ featl, float* __restrict__ io)
{
  constexpr int F = HEADS * D;
  int wid = threadIdx.x >> 6;
  int lane = threadIdx.x & 63;
  int node = blockIdx.x * 4 + wid;
  if (node >= N_NODES) return;
  int start = rowptr[node], end = rowptr[node + 1];
  float4 erd = *(const float4*)(er + 4 * node);

  // pass 1a: per-head max over in-edges (lanes parallel over edges)
  float m0 = -1e30f, m1 = -1e30f, m2 = -1e30f, m3 = -1e30f;
  for (int i = start + lane; i < end; i += 64){
    int s = csr_src[i];
    float4 e4 = *(const float4*)(el + 4 * s);
    m0 = fmaxf(m0, leaky(e4.x + erd.x));
    m1 = fmaxf(m1, leaky(e4.y + erd.y));
    m2 = fmaxf(m2, leaky(e4.z + erd.z));
    m3 = fmaxf(m3, leaky(e4.w + erd.w));
  }
  #pragma unroll
  for (int off = 32; off; off >>= 1){
    m0 = fmaxf(m0, __shfl_xor(m0, off, 64));
    m1 = fmaxf(m1, __shfl_xor(m1, off, 64));
    m2 = fmaxf(m2, __shfl_xor(m2, off, 64));
    m3 = fmaxf(m3, __shfl_xor(m3, off, 64));
  }
  // pass 1b: per-head denom
  float s0 = 0.f, s1 = 0.f, s2 = 0.f, s3 = 0.f;
  for (int i = start + lane; i < end; i += 64){
    int s = csr_src[i];
    float4 e4 = *(const float4*)(el + 4 * s);
    s0 += __expf(leaky(e4.x + erd.x) - m0);
    s1 += __expf(leaky(e4.y + erd.y) - m1);
    s2 += __expf(leaky(e4.z + erd.z) - m2);
    s3 += __expf(leaky(e4.w + erd.w) - m3);
  }
  #pragma unroll
  for (int off = 32; off; off >>= 1){
    s0 += __shfl_xor(s0, off, 64);
    s1 += __shfl_xor(s1, off, 64);
    s2 += __shfl_xor(s2, off, 64);
    s3 += __shfl_xor(s3, off, 64);
  }
  float i0 = 1.f / fmaxf(s0, 1e-16f);
  float i1 = 1.f / fmaxf(s1, 1e-16f);
  float i2 = 1.f / fmaxf(s2, 1e-16f);
  float i3 = 1.f / fmaxf(s3, 1e-16f);
  float4 mh = make_float4(m0, m1, m2, m3);
  float4 ih = make_float4(i0, i1, i2, i3);

  // pass 2: lanes over features, serial over edges; acc in registers
  const int f0 = lane;
  const int h0 = f0 / D;
  const float er0 = sel4(erd, h0), mm0 = sel4(mh, h0), ii0 = sel4(ih, h0);
  float acc0 = io[node * F + f0];
  float acc1 = 0.f, acc2 = 0.f;
  int h1 = 0, h2 = 3;
  float er1 = 0.f, mm1 = 0.f, ii1 = 0.f, er2 = 0.f, mm2 = 0.f, ii2 = 0.f;
  if (D == 40){
    h1 = (lane + 64) / D;
    er1 = sel4(erd, h1); mm1 = sel4(mh, h1); ii1 = sel4(ih, h1);
    acc1 = io[node * F + lane + 64];
    if (lane < F - 128){
      er2 = sel4(erd, h2); mm2 = sel4(mh, h2); ii2 = sel4(ih, h2);
      acc2 = io[node * F + lane + 128];
    }
  }
  for (int i = start; i < end; ++i){
    int s = csr_src[i];                         // uniform across wave
    float4 e4 = *(const float4*)(el + 4 * s);   // uniform across wave
    float a0 = __expf(leaky(sel4(e4, h0) + er0) - mm0) * ii0;
    acc0 += a0 * featl[s * F + f0];
    if (D == 40){
      float a1 = __expf(leaky(sel4(e4, h1) + er1) - mm1) * ii1;
      acc1 += a1 * featl[s * F + lane + 64];
      if (lane < F - 128){
        float a2 = __expf(leaky(sel4(e4, h2) + er2) - mm2) * ii2;
        acc2 += a2 * featl[s * F + lane + 128];
      }
    }
  }
  io[node * F + f0] = acc0;
  if (D == 40){
    io[node * F + lane + 64] = acc1;
    if (lane < F - 128) io[node * F + lane + 128] = acc2;
  }
}

// ---------------- BatchNorm ----------------
__global__ void bn_stats_kernel(const float* __restrict__ x, float* __restrict__ sums, int n){
  __shared__ float s[512];
  int tid = threadIdx.x;
  int f = tid & 63, g = tid >> 6;
  float sm = 0.f, sq = 0.f;
  for (int r = blockIdx.x * 4 + g; r < n; r += gridDim.x * 4){
    float v = x[r * 64 + f];
    sm += v; sq += v * v;
  }
  s[tid] = sm; s[256 + tid] = sq;
  __syncthreads();
  if (g == 0){
    float a = s[f] + s[64 + f] + s[128 + f] + s[192 + f];
    float b = s[256 + f] + s[320 + f] + s[384 + f] + s[448 + f];
    atomicAdd(&sums[f], a);
    atomicAdd(&sums[64 + f], b);
  }
}

__global__ void bn_finalize_kernel(float* __restrict__ stats, int n){
  int f = threadIdx.x;
  if (f < 64){
    float mu = stats[f] / n;
    float var = stats[64 + f] / n - mu * mu;
    stats[128 + f] = mu;
    stats[192 + f] = rsqrtf(var + BN_EPS);
  }
}

// in-place: x <- relu(bn(x))
__global__ void bn_apply_kernel(float* __restrict__ x, const float* __restrict__ stats,
                                const float* __restrict__ gamma, const float* __restrict__ beta,
                                int n){
  int idx = blockIdx.x * blockDim.x + threadIdx.x;
  if (idx >= n * 64) return;
  int f = idx & 63;
  float v = (x[idx] - stats[128 + f]) * stats[192 + f] * gamma[f] + beta[f];
  x[idx] = v > 0.f ? v : 0.f;
}

extern "C" void kernel_launch(void* const* d_in, const int* in_sizes, int n_in,
                              void* d_out, int out_size, void* d_ws, size_t ws_size,
                              hipStream_t stream){
  const float* feat  = (const float*)d_in[0];
  const int*   src   = (const int*)d_in[1];
  const int*   dst   = (const int*)d_in[2];
  const float* W0    = (const float*)d_in[3];
  const float* al0   = (const float*)d_in[4];
  const float* ar0   = (const float*)d_in[5];
  const float* b0    = (const float*)d_in[6];
  const float* resW0 = (const float*)d_in[7];
  const float* g0    = (const float*)d_in[8];
  const float* be0   = (const float*)d_in[9];
  const float* W1    = (const float*)d_in[10];
  const float* al1   = (const float*)d_in[11];
  const float* ar1   = (const float*)d_in[12];
  const float* b1    = (const float*)d_in[13];
  const float* g1    = (const float*)d_in[14];
  const float* be1   = (const float*)d_in[15];
  const float* W2    = (const float*)d_in[16];
  const float* al2   = (const float*)d_in[17];
  const float* ar2   = (const float*)d_in[18];
  const float* b2    = (const float*)d_in[19];
  const float* resW2 = (const float*)d_in[20];
  float* out = (float*)d_out;

  // workspace layout (floats then ints), ~100 MB total
  float* featl = (float*)d_ws;                    // N*160
  float* h     = featl + N_NODES * 160;           // N*64
  float* el    = h + N_NODES * 64;                // N*4
  float* er    = el + N_NODES * 4;                // N*4
  float* stats = er + N_NODES * 4;                // 256
  int* rowptr  = (int*)(stats + 256);             // N+1
  int* cursor  = rowptr + (N_NODES + 1);          // N
  int* deg     = cursor + N_NODES;                // N
  int* csr_src = deg + N_NODES;                   // E

  const int B = 256;
  const int gNH  = cdiv(N_NODES * HEADS, B);
  const int gE   = cdiv(N_EDGES, B);
  const int g64  = cdiv(N_NODES * 64, B);
  const int g160 = cdiv(N_NODES * 160, B);
  const int gN   = cdiv(N_NODES, B);
  const int gAgg = cdiv(N_NODES, 4);

  // ---------- CSR build (reused by all 3 layers) ----------
  fill_i32<<<gN, B, 0, stream>>>(deg, 0, N_NODES);
  hist_kernel<<<gE, B, 0, stream>>>(dst, deg);
  scan_kernel<<<1, 1024, 0, stream>>>(deg, rowptr, cursor);
  scatter_kernel<<<gE, B, 0, stream>>>(src, dst, cursor, csr_src);

  // ================= layer 0 =================
  gemm_kernel<<<g64, B, F_IN * 64 * 4, stream>>>(feat, W0, nullptr, featl, N_NODES, F_IN, 64);
  elr_kernel<<<gNH, B, 0, stream>>>(featl, al0, ar0, el, er, N_NODES, HID);
  gemm_kernel<<<g64, B, F_IN * 64 * 4, stream>>>(feat, resW0, b0, h, N_NODES, F_IN, 64);
  node_agg_kernel<HID><<<gAgg, B, 0, stream>>>(rowptr, csr_src, el, er, featl, h);
  fill_f32<<<1, 128, 0, stream>>>(stats, 0.f, 128);
  bn_stats_kernel<<<512, 256, 0, stream>>>(h, stats, N_NODES);
  bn_finalize_kernel<<<1, 64, 0, stream>>>(stats, N_NODES);
  bn_apply_kernel<<<g64, B, 0, stream>>>(h, stats, g0, be0, N_NODES);

  // ================= layer 1 =================
  gemm_kernel<<<g64, B, 64 * 64 * 4, stream>>>(h, W1, nullptr, featl, N_NODES, 64, 64);
  elr_kernel<<<gNH, B, 0, stream>>>(featl, al1, ar1, el, er, N_NODES, HID);
  residual2_kernel<<<g64, B, 0, stream>>>(h, b1, N_NODES, 64);
  node_agg_kernel<HID><<<gAgg, B, 0, stream>>>(rowptr, csr_src, el, er, featl, h);
  fill_f32<<<1, 128, 0, stream>>>(stats, 0.f, 128);
  bn_stats_kernel<<<512, 256, 0, stream>>>(h, stats, N_NODES);
  bn_finalize_kernel<<<1, 64, 0, stream>>>(stats, N_NODES);
  bn_apply_kernel<<<g64, B, 0, stream>>>(h, stats, g1, be1, N_NODES);

  // ================= layer 2 =================
  gemm_kernel<<<g160, B, 64 * 160 * 4, stream>>>(h, W2, nullptr, featl, N_NODES, 64, 160);
  elr_kernel<<<gNH, B, 0, stream>>>(featl, al2, ar2, el, er, N_NODES, OUTC);
  gemm_kernel<<<g160, B, 64 * 160 * 4, stream>>>(h, resW2, b2, out, N_NODES, 64, 160);
  node_agg_kernel<OUTC><<<gAgg, B, 0, stream>>>(rowptr, csr_src, el, er, featl, out);
}

// Round 3
// 1614.126 us; speedup vs baseline: 16.2585x; 1.6916x over previous
//
#include <hip/hip_runtime.h>
#include <cstdint>

#define N_NODES 100000
#define N_EDGES 1600000
#define F_IN 128
#define HID 16
#define HEADS 4
#define OUTC 40
#define NEG_SLOPE 0.2f
#define BN_EPS 1e-5f

static inline int cdiv(int a, int b){ return (a + b - 1) / b; }

__global__ void fill_f32(float* p, float v, int n){
  int i = blockIdx.x * blockDim.x + threadIdx.x;
  if (i < n) p[i] = v;
}
__global__ void fill_i32(int* p, int v, int n){
  int i = blockIdx.x * blockDim.x + threadIdx.x;
  if (i < n) p[i] = v;
}

// ---------------- tiled register-blocked GEMM ----------------
// C[n,M] = A[n,K] @ W[K,M] (+bias). One block = 64 rows x all M cols.
// A-tile (64 x K, padded to K+4) and all of W staged in LDS once; no k-tiling.
// Thread layout: CT = M/4 col-threads x RT row-threads; each thread owns
// RPT = 64/RT rows x 4 cols of output (float4 accumulators).
template<int K, int M, int RT>
__global__ __launch_bounds__((M / 4) * RT) void gemm_tiled(
    const float* __restrict__ A, const float* __restrict__ W,
    const float* __restrict__ bias, float* __restrict__ C, int n)
{
  constexpr int CT = M / 4;
  constexpr int BT = CT * RT;
  constexpr int ROWS = 64;
  constexpr int RPT = ROWS / RT;
  constexpr int KP = K + 4;                  // pad: row stride 16 banks -> <=2-way
  __shared__ float ash[ROWS * KP];
  __shared__ float wsh[K * M];

  const int t = threadIdx.x;
  const int row0 = blockIdx.x * ROWS;

  // stage W (coalesced float4)
  const float4* Wv = (const float4*)W;
  for (int q = t; q < K * M / 4; q += BT)
    *(float4*)&wsh[q * 4] = Wv[q];

  // stage A tile (coalesced float4 from row-major A)
  for (int q = t; q < ROWS * K / 4; q += BT){
    int r = q / (K / 4);
    int kq = q - r * (K / 4);
    int grow = row0 + r;
    float4 v = make_float4(0.f, 0.f, 0.f, 0.f);
    if (grow < n) v = *(const float4*)&A[grow * K + kq * 4];
    *(float4*)&ash[r * KP + kq * 4] = v;
  }
  __syncthreads();

  const int c = t % CT;
  const int rt = t / CT;
  const int r0 = rt * RPT;

  float4 bb = make_float4(0.f, 0.f, 0.f, 0.f);
  if (bias) bb = ((const float4*)bias)[c];
  float4 acc[RPT];
  #pragma unroll
  for (int r = 0; r < RPT; ++r) acc[r] = bb;

  for (int k0 = 0; k0 < K; k0 += 4){
    float4 w0 = *(const float4*)&wsh[(k0 + 0) * M + c * 4];
    float4 w1 = *(const float4*)&wsh[(k0 + 1) * M + c * 4];
    float4 w2 = *(const float4*)&wsh[(k0 + 2) * M + c * 4];
    float4 w3 = *(const float4*)&wsh[(k0 + 3) * M + c * 4];
    #pragma unroll
    for (int r = 0; r < RPT; ++r){
      float4 a = *(const float4*)&ash[(r0 + r) * KP + k0];
      acc[r].x += a.x * w0.x + a.y * w1.x + a.z * w2.x + a.w * w3.x;
      acc[r].y += a.x * w0.y + a.y * w1.y + a.z * w2.y + a.w * w3.y;
      acc[r].z += a.x * w0.z + a.y * w1.z + a.z * w2.z + a.w * w3.z;
      acc[r].w += a.x * w0.w + a.y * w1.w + a.z * w2.w + a.w * w3.w;
    }
  }

  #pragma unroll
  for (int r = 0; r < RPT; ++r){
    int row = row0 + r0 + r;
    if (row < n) *(float4*)&C[row * M + c * 4] = acc[r];
  }
}

// el[n,h] = sum_d featl[n,h,d]*al[h,d]; er likewise
__global__ void elr_kernel(const float* __restrict__ featl,
                           const float* __restrict__ al, const float* __restrict__ ar,
                           float* __restrict__ el, float* __restrict__ er,
                           int n, int D){
  int idx = blockIdx.x * blockDim.x + threadIdx.x;
  if (idx >= n * HEADS) return;
  int h = idx & (HEADS - 1);
  const float* f = featl + (idx >> 2) * (HEADS * D) + h * D;
  float sl = 0.f, sr = 0.f;
  for (int d = 0; d < D; ++d){
    float v = f[d];
    sl += v * al[h * D + d];
    sr += v * ar[h * D + d];
  }
  el[idx] = sl;
  er[idx] = sr;
}

// h = 2*h + b  (layer 1: identity res_fc + outer residual, fused; in-place)
__global__ void residual2_kernel(float* __restrict__ hh, const float* __restrict__ b, int n, int F){
  int idx = blockIdx.x * blockDim.x + threadIdx.x;
  if (idx >= n * F) return;
  int f = idx % F;
  hh[idx] = 2.f * hh[idx] + b[f];
}

// ---------------- CSR build ----------------
__global__ void hist_kernel(const int* __restrict__ dst, int* __restrict__ deg){
  int i = blockIdx.x * blockDim.x + threadIdx.x;
  if (i < N_EDGES) atomicAdd(&deg[dst[i]], 1);
}

__global__ void scan_kernel(const int* __restrict__ deg, int* __restrict__ rowptr,
                            int* __restrict__ cursor){
  __shared__ int part[1024];
  const int T = 1024;
  const int CH = (N_NODES + T - 1) / T;
  int t = threadIdx.x;
  int lo = t * CH, hi = min(lo + CH, N_NODES);
  int s = 0;
  for (int j = lo; j < hi; ++j) s += deg[j];
  part[t] = s;
  __syncthreads();
  for (int off = 1; off < T; off <<= 1){
    int v = part[t];
    int u = (t >= off) ? part[t - off] : 0;
    __syncthreads();
    part[t] = v + u;
    __syncthreads();
  }
  int run = (t > 0) ? part[t - 1] : 0;
  for (int j = lo; j < hi; ++j){
    rowptr[j] = run;
    cursor[j] = run;
    run += deg[j];
  }
  if (t == T - 1) rowptr[N_NODES] = N_EDGES;
}

__global__ void scatter_kernel(const int* __restrict__ src, const int* __restrict__ dst,
                               int* __restrict__ cursor, int* __restrict__ csr_src){
  int i = blockIdx.x * blockDim.x + threadIdx.x;
  if (i >= N_EDGES) return;
  int d = dst[i];
  int pos = atomicAdd(&cursor[d], 1);
  csr_src[pos] = src[i];
}

// ---------------- per-node softmax + aggregation (gather, no atomics) ----------------
__device__ __forceinline__ float leaky(float x){ return x >= 0.f ? x : NEG_SLOPE * x; }
__device__ __forceinline__ float sel4(float4 v, int h){
  float r = v.x;
  r = (h == 1) ? v.y : r;
  r = (h == 2) ? v.z : r;
  r = (h == 3) ? v.w : r;
  return r;
}

template<int D>
__global__ __launch_bounds__(256) void node_agg_kernel(
    const int* __restrict__ rowptr, const int* __restrict__ csr_src,
    const float* __restrict__ el, const float* __restrict__ er,
    const float* __restrict__ featl, float* __restrict__ io)
{
  constexpr int F = HEADS * D;
  int wid = threadIdx.x >> 6;
  int lane = threadIdx.x & 63;
  int node = blockIdx.x * 4 + wid;
  if (node >= N_NODES) return;
  int start = rowptr[node], end = rowptr[node + 1];
  float4 erd = *(const float4*)(er + 4 * node);

  float m0 = -1e30f, m1 = -1e30f, m2 = -1e30f, m3 = -1e30f;
  for (int i = start + lane; i < end; i += 64){
    int s = csr_src[i];
    float4 e4 = *(const float4*)(el + 4 * s);
    m0 = fmaxf(m0, leaky(e4.x + erd.x));
    m1 = fmaxf(m1, leaky(e4.y + erd.y));
    m2 = fmaxf(m2, leaky(e4.z + erd.z));
    m3 = fmaxf(m3, leaky(e4.w + erd.w));
  }
  #pragma unroll
  for (int off = 32; off; off >>= 1){
    m0 = fmaxf(m0, __shfl_xor(m0, off, 64));
    m1 = fmaxf(m1, __shfl_xor(m1, off, 64));
    m2 = fmaxf(m2, __shfl_xor(m2, off, 64));
    m3 = fmaxf(m3, __shfl_xor(m3, off, 64));
  }
  float s0 = 0.f, s1 = 0.f, s2 = 0.f, s3 = 0.f;
  for (int i = start + lane; i < end; i += 64){
    int s = csr_src[i];
    float4 e4 = *(const float4*)(el + 4 * s);
    s0 += __expf(leaky(e4.x + erd.x) - m0);
    s1 += __expf(leaky(e4.y + erd.y) - m1);
    s2 += __expf(leaky(e4.z + erd.z) - m2);
    s3 += __expf(leaky(e4.w + erd.w) - m3);
  }
  #pragma unroll
  for (int off = 32; off; off >>= 1){
    s0 += __shfl_xor(s0, off, 64);
    s1 += __shfl_xor(s1, off, 64);
    s2 += __shfl_xor(s2, off, 64);
    s3 += __shfl_xor(s3, off, 64);
  }
  float i0 = 1.f / fmaxf(s0, 1e-16f);
  float i1 = 1.f / fmaxf(s1, 1e-16f);
  float i2 = 1.f / fmaxf(s2, 1e-16f);
  float i3 = 1.f / fmaxf(s3, 1e-16f);
  float4 mh = make_float4(m0, m1, m2, m3);
  float4 ih = make_float4(i0, i1, i2, i3);

  const int f0 = lane;
  const int h0 = f0 / D;
  const float er0 = sel4(erd, h0), mm0 = sel4(mh, h0), ii0 = sel4(ih, h0);
  float acc0 = io[node * F + f0];
  float acc1 = 0.f, acc2 = 0.f;
  int h1 = 0, h2 = 3;
  float er1 = 0.f, mm1 = 0.f, ii1 = 0.f, er2 = 0.f, mm2 = 0.f, ii2 = 0.f;
  if (D == 40){
    h1 = (lane + 64) / D;
    er1 = sel4(erd, h1); mm1 = sel4(mh, h1); ii1 = sel4(ih, h1);
    acc1 = io[node * F + lane + 64];
    if (lane < F - 128){
      er2 = sel4(erd, h2); mm2 = sel4(mh, h2); ii2 = sel4(ih, h2);
      acc2 = io[node * F + lane + 128];
    }
  }
  for (int i = start; i < end; ++i){
    int s = csr_src[i];
    float4 e4 = *(const float4*)(el + 4 * s);
    float a0 = __expf(leaky(sel4(e4, h0) + er0) - mm0) * ii0;
    acc0 += a0 * featl[s * F + f0];
    if (D == 40){
      float a1 = __expf(leaky(sel4(e4, h1) + er1) - mm1) * ii1;
      acc1 += a1 * featl[s * F + lane + 64];
      if (lane < F - 128){
        float a2 = __expf(leaky(sel4(e4, h2) + er2) - mm2) * ii2;
        acc2 += a2 * featl[s * F + lane + 128];
      }
    }
  }
  io[node * F + f0] = acc0;
  if (D == 40){
    io[node * F + lane + 64] = acc1;
    if (lane < F - 128) io[node * F + lane + 128] = acc2;
  }
}

// ---------------- BatchNorm ----------------
__global__ void bn_stats_kernel(const float* __restrict__ x, float* __restrict__ sums, int n){
  __shared__ float s[512];
  int tid = threadIdx.x;
  int f = tid & 63, g = tid >> 6;
  float sm = 0.f, sq = 0.f;
  for (int r = blockIdx.x * 4 + g; r < n; r += gridDim.x * 4){
    float v = x[r * 64 + f];
    sm += v; sq += v * v;
  }
  s[tid] = sm; s[256 + tid] = sq;
  __syncthreads();
  if (g == 0){
    float a = s[f] + s[64 + f] + s[128 + f] + s[192 + f];
    float b = s[256 + f] + s[320 + f] + s[384 + f] + s[448 + f];
    atomicAdd(&sums[f], a);
    atomicAdd(&sums[64 + f], b);
  }
}

__global__ void bn_finalize_kernel(float* __restrict__ stats, int n){
  int f = threadIdx.x;
  if (f < 64){
    float mu = stats[f] / n;
    float var = stats[64 + f] / n - mu * mu;
    stats[128 + f] = mu;
    stats[192 + f] = rsqrtf(var + BN_EPS);
  }
}

__global__ void bn_apply_kernel(float* __restrict__ x, const float* __restrict__ stats,
                                const float* __restrict__ gamma, const float* __restrict__ beta,
                                int n){
  int idx = blockIdx.x * blockDim.x + threadIdx.x;
  if (idx >= n * 64) return;
  int f = idx & 63;
  float v = (x[idx] - stats[128 + f]) * stats[192 + f] * gamma[f] + beta[f];
  x[idx] = v > 0.f ? v : 0.f;
}

extern "C" void kernel_launch(void* const* d_in, const int* in_sizes, int n_in,
                              void* d_out, int out_size, void* d_ws, size_t ws_size,
                              hipStream_t stream){
  const float* feat  = (const float*)d_in[0];
  const int*   src   = (const int*)d_in[1];
  const int*   dst   = (const int*)d_in[2];
  const float* W0    = (const float*)d_in[3];
  const float* al0   = (const float*)d_in[4];
  const float* ar0   = (const float*)d_in[5];
  const float* b0    = (const float*)d_in[6];
  const float* resW0 = (const float*)d_in[7];
  const float* g0    = (const float*)d_in[8];
  const float* be0   = (const float*)d_in[9];
  const float* W1    = (const float*)d_in[10];
  const float* al1   = (const float*)d_in[11];
  const float* ar1   = (const float*)d_in[12];
  const float* b1    = (const float*)d_in[13];
  const float* g1    = (const float*)d_in[14];
  const float* be1   = (const float*)d_in[15];
  const float* W2    = (const float*)d_in[16];
  const float* al2   = (const float*)d_in[17];
  const float* ar2   = (const float*)d_in[18];
  const float* b2    = (const float*)d_in[19];
  const float* resW2 = (const float*)d_in[20];
  float* out = (float*)d_out;

  float* featl = (float*)d_ws;                    // N*160
  float* h     = featl + N_NODES * 160;           // N*64
  float* el    = h + N_NODES * 64;                // N*4
  float* er    = el + N_NODES * 4;                // N*4
  float* stats = er + N_NODES * 4;                // 256
  int* rowptr  = (int*)(stats + 256);             // N+1
  int* cursor  = rowptr + (N_NODES + 1);          // N
  int* deg     = cursor + N_NODES;                // N
  int* csr_src = deg + N_NODES;                   // E

  const int B = 256;
  const int gNH  = cdiv(N_NODES * HEADS, B);
  const int gE   = cdiv(N_EDGES, B);
  const int g64  = cdiv(N_NODES * 64, B);
  const int gN   = cdiv(N_NODES, B);
  const int gAgg = cdiv(N_NODES, 4);
  const int gGemm = cdiv(N_NODES, 64);

  // ---------- CSR build (reused by all 3 layers) ----------
  fill_i32<<<gN, B, 0, stream>>>(deg, 0, N_NODES);
  hist_kernel<<<gE, B, 0, stream>>>(dst, deg);
  scan_kernel<<<1, 1024, 0, stream>>>(deg, rowptr, cursor);
  scatter_kernel<<<gE, B, 0, stream>>>(src, dst, cursor, csr_src);

  // ================= layer 0 =================
  gemm_tiled<128, 64, 16><<<gGemm, 256, 0, stream>>>(feat, W0, nullptr, featl, N_NODES);
  elr_kernel<<<gNH, B, 0, stream>>>(featl, al0, ar0, el, er, N_NODES, HID);
  gemm_tiled<128, 64, 16><<<gGemm, 256, 0, stream>>>(feat, resW0, b0, h, N_NODES);
  node_agg_kernel<HID><<<gAgg, 256, 0, stream>>>(rowptr, csr_src, el, er, featl, h);
  fill_f32<<<1, 128, 0, stream>>>(stats, 0.f, 128);
  bn_stats_kernel<<<512, 256, 0, stream>>>(h, stats, N_NODES);
  bn_finalize_kernel<<<1, 64, 0, stream>>>(stats, N_NODES);
  bn_apply_kernel<<<g64, B, 0, stream>>>(h, stats, g0, be0, N_NODES);

  // ================= layer 1 =================
  gemm_tiled<64, 64, 16><<<gGemm, 256, 0, stream>>>(h, W1, nullptr, featl, N_NODES);
  elr_kernel<<<gNH, B, 0, stream>>>(featl, al1, ar1, el, er, N_NODES, HID);
  residual2_kernel<<<g64, B, 0, stream>>>(h, b1, N_NODES, 64);
  node_agg_kernel<HID><<<gAgg, 256, 0, stream>>>(rowptr, csr_src, el, er, featl, h);
  fill_f32<<<1, 128, 0, stream>>>(stats, 0.f, 128);
  bn_stats_kernel<<<512, 256, 0, stream>>>(h, stats, N_NODES);
  bn_finalize_kernel<<<1, 64, 0, stream>>>(stats, N_NODES);
  bn_apply_kernel<<<g64, B, 0, stream>>>(h, stats, g1, be1, N_NODES);

  // ================= layer 2 =================
  gemm_tiled<64, 160, 8><<<gGemm, 320, 0, stream>>>(h, W2, nullptr, featl, N_NODES);
  elr_kernel<<<gNH, B, 0, stream>>>(featl, al2, ar2, el, er, N_NODES, OUTC);
  gemm_tiled<64, 160, 8><<<gGemm, 320, 0, stream>>>(h, resW2, b2, out, N_NODES);
  node_agg_kernel<OUTC><<<gAgg, 256, 0, stream>>>(rowptr, csr_src, el, er, featl, out);
}

// Round 4
// 1362.519 us; speedup vs baseline: 19.2608x; 1.1847x over previous
//
#include <hip/hip_runtime.h>
#include <cstdint>

#define N_NODES 100000
#define N_EDGES 1600000
#define F_IN 128
#define HID 16
#define HEADS 4
#define OUTC 40
#define NEG_SLOPE 0.2f
#define BN_EPS 1e-5f

static inline int cdiv(int a, int b){ return (a + b - 1) / b; }

__device__ __forceinline__ float bf2f(unsigned short u){
  union { unsigned u32; float f; } v; v.u32 = ((unsigned)u) << 16; return v.f;
}
__device__ __forceinline__ unsigned short f2bf(float x){
  union { float f; unsigned u; } v; v.f = x;
  unsigned r = v.u + 0x7FFFu + ((v.u >> 16) & 1u);
  return (unsigned short)(r >> 16);
}

__global__ void fill_f32(float* p, float v, int n){
  int i = blockIdx.x * blockDim.x + threadIdx.x;
  if (i < n) p[i] = v;
}
__global__ void fill_i32(int* p, int v, int n){
  int i = blockIdx.x * blockDim.x + threadIdx.x;
  if (i < n) p[i] = v;
}

// ---------------- tiled register-blocked GEMM ----------------
// C[n,M] = A[n,K] @ W[K,M] (+bias). One block = 64 rows x all M cols.
// BF16OUT: store C as bf16 (ushort), else fp32.
template<int K, int M, int RT, bool BF16OUT>
__global__ __launch_bounds__((M / 4) * RT) void gemm_tiled(
    const float* __restrict__ A, const float* __restrict__ W,
    const float* __restrict__ bias, void* __restrict__ Cv, int n)
{
  constexpr int CT = M / 4;
  constexpr int BT = CT * RT;
  constexpr int ROWS = 64;
  constexpr int RPT = ROWS / RT;
  constexpr int KP = K + 4;
  __shared__ float ash[ROWS * KP];
  __shared__ float wsh[K * M];

  const int t = threadIdx.x;
  const int row0 = blockIdx.x * ROWS;

  const float4* Wv = (const float4*)W;
  for (int q = t; q < K * M / 4; q += BT)
    *(float4*)&wsh[q * 4] = Wv[q];

  for (int q = t; q < ROWS * K / 4; q += BT){
    int r = q / (K / 4);
    int kq = q - r * (K / 4);
    int grow = row0 + r;
    float4 v = make_float4(0.f, 0.f, 0.f, 0.f);
    if (grow < n) v = *(const float4*)&A[grow * K + kq * 4];
    *(float4*)&ash[r * KP + kq * 4] = v;
  }
  __syncthreads();

  const int c = t % CT;
  const int rt = t / CT;
  const int r0 = rt * RPT;

  float4 bb = make_float4(0.f, 0.f, 0.f, 0.f);
  if (bias) bb = ((const float4*)bias)[c];
  float4 acc[RPT];
  #pragma unroll
  for (int r = 0; r < RPT; ++r) acc[r] = bb;

  for (int k0 = 0; k0 < K; k0 += 4){
    float4 w0 = *(const float4*)&wsh[(k0 + 0) * M + c * 4];
    float4 w1 = *(const float4*)&wsh[(k0 + 1) * M + c * 4];
    float4 w2 = *(const float4*)&wsh[(k0 + 2) * M + c * 4];
    float4 w3 = *(const float4*)&wsh[(k0 + 3) * M + c * 4];
    #pragma unroll
    for (int r = 0; r < RPT; ++r){
      float4 a = *(const float4*)&ash[(r0 + r) * KP + k0];
      acc[r].x += a.x * w0.x + a.y * w1.x + a.z * w2.x + a.w * w3.x;
      acc[r].y += a.x * w0.y + a.y * w1.y + a.z * w2.y + a.w * w3.y;
      acc[r].z += a.x * w0.z + a.y * w1.z + a.z * w2.z + a.w * w3.z;
      acc[r].w += a.x * w0.w + a.y * w1.w + a.z * w2.w + a.w * w3.w;
    }
  }

  #pragma unroll
  for (int r = 0; r < RPT; ++r){
    int row = row0 + r0 + r;
    if (row < n){
      if (BF16OUT){
        ushort4 o;
        o.x = f2bf(acc[r].x); o.y = f2bf(acc[r].y);
        o.z = f2bf(acc[r].z); o.w = f2bf(acc[r].w);
        *(ushort4*)&((unsigned short*)Cv)[row * M + c * 4] = o;
      } else {
        *(float4*)&((float*)Cv)[row * M + c * 4] = acc[r];
      }
    }
  }
}

// el[n,h] = sum_d featl[n,h,d]*al[h,d]; er likewise (featl is bf16)
__global__ void elr_kernel(const unsigned short* __restrict__ featl,
                           const float* __restrict__ al, const float* __restrict__ ar,
                           float* __restrict__ el, float* __restrict__ er,
                           int n, int D){
  int idx = blockIdx.x * blockDim.x + threadIdx.x;
  if (idx >= n * HEADS) return;
  int h = idx & (HEADS - 1);
  const unsigned short* f = featl + (idx >> 2) * (HEADS * D) + h * D;
  float sl = 0.f, sr = 0.f;
  for (int d = 0; d < D; ++d){
    float v = bf2f(f[d]);
    sl += v * al[h * D + d];
    sr += v * ar[h * D + d];
  }
  el[idx] = sl;
  er[idx] = sr;
}

__global__ void residual2_kernel(float* __restrict__ hh, const float* __restrict__ b, int n, int F){
  int idx = blockIdx.x * blockDim.x + threadIdx.x;
  if (idx >= n * F) return;
  int f = idx % F;
  hh[idx] = 2.f * hh[idx] + b[f];
}

// ---------------- CSR build ----------------
__global__ void hist_kernel(const int* __restrict__ dst, int* __restrict__ deg){
  int i = blockIdx.x * blockDim.x + threadIdx.x;
  if (i < N_EDGES) atomicAdd(&deg[dst[i]], 1);
}

__global__ void scan_kernel(const int* __restrict__ deg, int* __restrict__ rowptr,
                            int* __restrict__ cursor){
  __shared__ int part[1024];
  const int T = 1024;
  const int CH = (N_NODES + T - 1) / T;
  int t = threadIdx.x;
  int lo = t * CH, hi = min(lo + CH, N_NODES);
  int s = 0;
  for (int j = lo; j < hi; ++j) s += deg[j];
  part[t] = s;
  __syncthreads();
  for (int off = 1; off < T; off <<= 1){
    int v = part[t];
    int u = (t >= off) ? part[t - off] : 0;
    __syncthreads();
    part[t] = v + u;
    __syncthreads();
  }
  int run = (t > 0) ? part[t - 1] : 0;
  for (int j = lo; j < hi; ++j){
    rowptr[j] = run;
    cursor[j] = run;
    run += deg[j];
  }
  if (t == T - 1) rowptr[N_NODES] = N_EDGES;
}

__global__ void scatter_kernel(const int* __restrict__ src, const int* __restrict__ dst,
                               int* __restrict__ cursor, int* __restrict__ csr_src){
  int i = blockIdx.x * blockDim.x + threadIdx.x;
  if (i >= N_EDGES) return;
  int d = dst[i];
  int pos = atomicAdd(&cursor[d], 1);
  csr_src[pos] = src[i];
}

// ---------------- per-node softmax + aggregation ----------------
__device__ __forceinline__ float leaky(float x){ return x >= 0.f ? x : NEG_SLOPE * x; }
__device__ __forceinline__ float sel4(float4 v, int h){
  float r = v.x;
  r = (h == 1) ? v.y : r;
  r = (h == 2) ? v.z : r;
  r = (h == 3) ? v.w : r;
  return r;
}

template<int D>
__global__ __launch_bounds__(256) void node_agg_kernel(
    const int* __restrict__ rowptr, const int* __restrict__ csr_src,
    const float* __restrict__ el, const float* __restrict__ er,
    const unsigned short* __restrict__ featl, float* __restrict__ io)
{
  constexpr int F = HEADS * D;
  int wid = threadIdx.x >> 6;
  int lane = threadIdx.x & 63;
  int node = blockIdx.x * 4 + wid;
  if (node >= N_NODES) return;
  int start = rowptr[node], end = rowptr[node + 1];
  int cnt = end - start;
  float4 erd = *(const float4*)(er + 4 * node);

  float m0, m1, m2, m3, s0, s1, s2, s3;
  if (cnt <= 64){
    // single gather: each lane holds <=1 edge logit
    float x0 = -1e30f, x1 = -1e30f, x2 = -1e30f, x3 = -1e30f;
    if (lane < cnt){
      int s = csr_src[start + lane];
      float4 e4 = *(const float4*)(el + 4 * s);
      x0 = leaky(e4.x + erd.x); x1 = leaky(e4.y + erd.y);
      x2 = leaky(e4.z + erd.z); x3 = leaky(e4.w + erd.w);
    }
    m0 = x0; m1 = x1; m2 = x2; m3 = x3;
    #pragma unroll
    for (int off = 32; off; off >>= 1){
      m0 = fmaxf(m0, __shfl_xor(m0, off, 64));
      m1 = fmaxf(m1, __shfl_xor(m1, off, 64));
      m2 = fmaxf(m2, __shfl_xor(m2, off, 64));
      m3 = fmaxf(m3, __shfl_xor(m3, off, 64));
    }
    float e0 = 0.f, e1 = 0.f, e2 = 0.f, e3 = 0.f;
    if (lane < cnt){
      e0 = __expf(x0 - m0); e1 = __expf(x1 - m1);
      e2 = __expf(x2 - m2); e3 = __expf(x3 - m3);
    }
    s0 = e0; s1 = e1; s2 = e2; s3 = e3;
    #pragma unroll
    for (int off = 32; off; off >>= 1){
      s0 += __shfl_xor(s0, off, 64);
      s1 += __shfl_xor(s1, off, 64);
      s2 += __shfl_xor(s2, off, 64);
      s3 += __shfl_xor(s3, off, 64);
    }
  } else {
    // two-pass fallback (deg > 64, rare)
    m0 = -1e30f; m1 = -1e30f; m2 = -1e30f; m3 = -1e30f;
    for (int i = start + lane; i < end; i += 64){
      int s = csr_src[i];
      float4 e4 = *(const float4*)(el + 4 * s);
      m0 = fmaxf(m0, leaky(e4.x + erd.x));
      m1 = fmaxf(m1, leaky(e4.y + erd.y));
      m2 = fmaxf(m2, leaky(e4.z + erd.z));
      m3 = fmaxf(m3, leaky(e4.w + erd.w));
    }
    #pragma unroll
    for (int off = 32; off; off >>= 1){
      m0 = fmaxf(m0, __shfl_xor(m0, off, 64));
      m1 = fmaxf(m1, __shfl_xor(m1, off, 64));
      m2 = fmaxf(m2, __shfl_xor(m2, off, 64));
      m3 = fmaxf(m3, __shfl_xor(m3, off, 64));
    }
    s0 = 0.f; s1 = 0.f; s2 = 0.f; s3 = 0.f;
    for (int i = start + lane; i < end; i += 64){
      int s = csr_src[i];
      float4 e4 = *(const float4*)(el + 4 * s);
      s0 += __expf(leaky(e4.x + erd.x) - m0);
      s1 += __expf(leaky(e4.y + erd.y) - m1);
      s2 += __expf(leaky(e4.z + erd.z) - m2);
      s3 += __expf(leaky(e4.w + erd.w) - m3);
    }
    #pragma unroll
    for (int off = 32; off; off >>= 1){
      s0 += __shfl_xor(s0, off, 64);
      s1 += __shfl_xor(s1, off, 64);
      s2 += __shfl_xor(s2, off, 64);
      s3 += __shfl_xor(s3, off, 64);
    }
  }
  float4 mh = make_float4(m0, m1, m2, m3);
  float4 ih = make_float4(1.f / fmaxf(s0, 1e-16f), 1.f / fmaxf(s1, 1e-16f),
                          1.f / fmaxf(s2, 1e-16f), 1.f / fmaxf(s3, 1e-16f));

  // pass 2: lanes over features, serial over edges, unrolled for MLP
  const int f0 = lane;
  const int h0 = f0 / D;
  const float er0 = sel4(erd, h0), mm0 = sel4(mh, h0), ii0 = sel4(ih, h0);
  float acc0 = io[node * F + f0];
  const unsigned short* fb = featl + f0;

  if (D == 16){
    int i = start;
    int e4i = start + (cnt & ~3);
    for (; i < e4i; i += 4){
      int sA = csr_src[i], sB = csr_src[i + 1], sC = csr_src[i + 2], sD = csr_src[i + 3];
      float4 eA = *(const float4*)(el + 4 * sA);
      float4 eB = *(const float4*)(el + 4 * sB);
      float4 eC = *(const float4*)(el + 4 * sC);
      float4 eD = *(const float4*)(el + 4 * sD);
      float fA = bf2f(fb[sA * F]);
      float fB = bf2f(fb[sB * F]);
      float fC = bf2f(fb[sC * F]);
      float fD = bf2f(fb[sD * F]);
      acc0 += __expf(leaky(sel4(eA, h0) + er0) - mm0) * ii0 * fA;
      acc0 += __expf(leaky(sel4(eB, h0) + er0) - mm0) * ii0 * fB;
      acc0 += __expf(leaky(sel4(eC, h0) + er0) - mm0) * ii0 * fC;
      acc0 += __expf(leaky(sel4(eD, h0) + er0) - mm0) * ii0 * fD;
    }
    for (; i < end; ++i){
      int s = csr_src[i];
      float4 e4 = *(const float4*)(el + 4 * s);
      acc0 += __expf(leaky(sel4(e4, h0) + er0) - mm0) * ii0 * bf2f(fb[s * F]);
    }
    io[node * F + f0] = acc0;
  } else {
    // D == 40: 3 feature loads per edge (f0, f0+64, f0+128 for lane<32)
    const int h1 = (lane + 64) / D;
    const int h2 = 3;
    const float er1 = sel4(erd, h1), mm1 = sel4(mh, h1), ii1 = sel4(ih, h1);
    const float er2 = sel4(erd, h2), mm2 = sel4(mh, h2), ii2 = sel4(ih, h2);
    float acc1 = io[node * F + lane + 64];
    float acc2 = (lane < F - 128) ? io[node * F + lane + 128] : 0.f;
    int i = start;
    int e2i = start + (cnt & ~1);
    for (; i < e2i; i += 2){
      int sA = csr_src[i], sB = csr_src[i + 1];
      float4 eA = *(const float4*)(el + 4 * sA);
      float4 eB = *(const float4*)(el + 4 * sB);
      float fA0 = bf2f(fb[sA * F]);
      float fA1 = bf2f(fb[sA * F + 64]);
      float fA2 = (lane < F - 128) ? bf2f(fb[sA * F + 128]) : 0.f;
      float fB0 = bf2f(fb[sB * F]);
      float fB1 = bf2f(fb[sB * F + 64]);
      float fB2 = (lane < F - 128) ? bf2f(fb[sB * F + 128]) : 0.f;
      acc0 += __expf(leaky(sel4(eA, h0) + er0) - mm0) * ii0 * fA0;
      acc1 += __expf(leaky(sel4(eA, h1) + er1) - mm1) * ii1 * fA1;
      acc2 += __expf(leaky(sel4(eA, h2) + er2) - mm2) * ii2 * fA2;
      acc0 += __expf(leaky(sel4(eB, h0) + er0) - mm0) * ii0 * fB0;
      acc1 += __expf(leaky(sel4(eB, h1) + er1) - mm1) * ii1 * fB1;
      acc2 += __expf(leaky(sel4(eB, h2) + er2) - mm2) * ii2 * fB2;
    }
    for (; i < end; ++i){
      int s = csr_src[i];
      float4 e4 = *(const float4*)(el + 4 * s);
      acc0 += __expf(leaky(sel4(e4, h0) + er0) - mm0) * ii0 * bf2f(fb[s * F]);
      acc1 += __expf(leaky(sel4(e4, h1) + er1) - mm1) * ii1 * bf2f(fb[s * F + 64]);
      if (lane < F - 128)
        acc2 += __expf(leaky(sel4(e4, h2) + er2) - mm2) * ii2 * bf2f(fb[s * F + 128]);
    }
    io[node * F + f0] = acc0;
    io[node * F + lane + 64] = acc1;
    if (lane < F - 128) io[node * F + lane + 128] = acc2;
  }
}

// ---------------- BatchNorm ----------------
__global__ void bn_stats_kernel(const float* __restrict__ x, float* __restrict__ sums, int n){
  __shared__ float s[512];
  int tid = threadIdx.x;
  int f = tid & 63, g = tid >> 6;
  float sm = 0.f, sq = 0.f;
  for (int r = blockIdx.x * 4 + g; r < n; r += gridDim.x * 4){
    float v = x[r * 64 + f];
    sm += v; sq += v * v;
  }
  s[tid] = sm; s[256 + tid] = sq;
  __syncthreads();
  if (g == 0){
    float a = s[f] + s[64 + f] + s[128 + f] + s[192 + f];
    float b = s[256 + f] + s[320 + f] + s[384 + f] + s[448 + f];
    atomicAdd(&sums[f], a);
    atomicAdd(&sums[64 + f], b);
  }
}

__global__ void bn_finalize_kernel(float* __restrict__ stats, int n){
  int f = threadIdx.x;
  if (f < 64){
    float mu = stats[f] / n;
    float var = stats[64 + f] / n - mu * mu;
    stats[128 + f] = mu;
    stats[192 + f] = rsqrtf(var + BN_EPS);
  }
}

__global__ void bn_apply_kernel(float* __restrict__ x, const float* __restrict__ stats,
                                const float* __restrict__ gamma, const float* __restrict__ beta,
                                int n){
  int idx = blockIdx.x * blockDim.x + threadIdx.x;
  if (idx >= n * 64) return;
  int f = idx & 63;
  float v = (x[idx] - stats[128 + f]) * stats[192 + f] * gamma[f] + beta[f];
  x[idx] = v > 0.f ? v : 0.f;
}

extern "C" void kernel_launch(void* const* d_in, const int* in_sizes, int n_in,
                              void* d_out, int out_size, void* d_ws, size_t ws_size,
                              hipStream_t stream){
  const float* feat  = (const float*)d_in[0];
  const int*   src   = (const int*)d_in[1];
  const int*   dst   = (const int*)d_in[2];
  const float* W0    = (const float*)d_in[3];
  const float* al0   = (const float*)d_in[4];
  const float* ar0   = (const float*)d_in[5];
  const float* b0    = (const float*)d_in[6];
  const float* resW0 = (const float*)d_in[7];
  const float* g0    = (const float*)d_in[8];
  const float* be0   = (const float*)d_in[9];
  const float* W1    = (const float*)d_in[10];
  const float* al1   = (const float*)d_in[11];
  const float* ar1   = (const float*)d_in[12];
  const float* b1    = (const float*)d_in[13];
  const float* g1    = (const float*)d_in[14];
  const float* be1   = (const float*)d_in[15];
  const float* W2    = (const float*)d_in[16];
  const float* al2   = (const float*)d_in[17];
  const float* ar2   = (const float*)d_in[18];
  const float* b2    = (const float*)d_in[19];
  const float* resW2 = (const float*)d_in[20];
  float* out = (float*)d_out;

  unsigned short* featl = (unsigned short*)d_ws;          // N*160 bf16
  float* h     = (float*)(featl + N_NODES * 160);         // N*64 f32
  float* el    = h + N_NODES * 64;                        // N*4
  float* er    = el + N_NODES * 4;                        // N*4
  float* stats = er + N_NODES * 4;                        // 256
  int* rowptr  = (int*)(stats + 256);                     // N+1
  int* cursor  = rowptr + (N_NODES + 1);                  // N
  int* deg     = cursor + N_NODES;                        // N
  int* csr_src = deg + N_NODES;                           // E

  const int B = 256;
  const int gNH  = cdiv(N_NODES * HEADS, B);
  const int gE   = cdiv(N_EDGES, B);
  const int g64  = cdiv(N_NODES * 64, B);
  const int gN   = cdiv(N_NODES, B);
  const int gAgg = cdiv(N_NODES, 4);
  const int gGemm = cdiv(N_NODES, 64);

  // ---------- CSR build (reused by all 3 layers) ----------
  fill_i32<<<gN, B, 0, stream>>>(deg, 0, N_NODES);
  hist_kernel<<<gE, B, 0, stream>>>(dst, deg);
  scan_kernel<<<1, 1024, 0, stream>>>(deg, rowptr, cursor);
  scatter_kernel<<<gE, B, 0, stream>>>(src, dst, cursor, csr_src);

  // ================= layer 0 =================
  gemm_tiled<128, 64, 16, true><<<gGemm, 256, 0, stream>>>(feat, W0, nullptr, featl, N_NODES);
  elr_kernel<<<gNH, B, 0, stream>>>(featl, al0, ar0, el, er, N_NODES, HID);
  gemm_tiled<128, 64, 16, false><<<gGemm, 256, 0, stream>>>(feat, resW0, b0, h, N_NODES);
  node_agg_kernel<HID><<<gAgg, 256, 0, stream>>>(rowptr, csr_src, el, er, featl, h);
  fill_f32<<<1, 128, 0, stream>>>(stats, 0.f, 128);
  bn_stats_kernel<<<512, 256, 0, stream>>>(h, stats, N_NODES);
  bn_finalize_kernel<<<1, 64, 0, stream>>>(stats, N_NODES);
  bn_apply_kernel<<<g64, B, 0, stream>>>(h, stats, g0, be0, N_NODES);

  // ================= layer 1 =================
  gemm_tiled<64, 64, 16, true><<<gGemm, 256, 0, stream>>>(h, W1, nullptr, featl, N_NODES);
  elr_kernel<<<gNH, B, 0, stream>>>(featl, al1, ar1, el, er, N_NODES, HID);
  residual2_kernel<<<g64, B, 0, stream>>>(h, b1, N_NODES, 64);
  node_agg_kernel<HID><<<gAgg, 256, 0, stream>>>(rowptr, csr_src, el, er, featl, h);
  fill_f32<<<1, 128, 0, stream>>>(stats, 0.f, 128);
  bn_stats_kernel<<<512, 256, 0, stream>>>(h, stats, N_NODES);
  bn_finalize_kernel<<<1, 64, 0, stream>>>(stats, N_NODES);
  bn_apply_kernel<<<g64, B, 0, stream>>>(h, stats, g1, be1, N_NODES);

  // ================= layer 2 =================
  gemm_tiled<64, 160, 8, true><<<gGemm, 320, 0, stream>>>(h, W2, nullptr, featl, N_NODES);
  elr_kernel<<<gNH, B, 0, stream>>>(featl, al2, ar2, el, er, N_NODES, OUTC);
  gemm_tiled<64, 160, 8, false><<<gGemm, 320, 0, stream>>>(h, resW2, b2, out, N_NODES);
  node_agg_kernel<OUTC><<<gAgg, 256, 0, stream>>>(rowptr, csr_src, el, er, featl, out);
}

// Round 5
// 1143.104 us; speedup vs baseline: 22.9578x; 1.1919x over previous
//
#include <hip/hip_runtime.h>
#include <cstdint>

#define N_NODES 100000
#define N_EDGES 1600000
#define F_IN 128
#define HID 16
#define HEADS 4
#define OUTC 40
#define NEG_SLOPE 0.2f
#define BN_EPS 1e-5f

#define SCAN_B 256
#define SCAN_NB ((N_NODES + SCAN_B - 1) / SCAN_B)   // 391

static inline int cdiv(int a, int b){ return (a + b - 1) / b; }

__device__ __forceinline__ float bf2f(unsigned short u){
  union { unsigned u32; float f; } v; v.u32 = ((unsigned)u) << 16; return v.f;
}
__device__ __forceinline__ unsigned short f2bf(float x){
  union { float f; unsigned u; } v; v.f = x;
  unsigned r = v.u + 0x7FFFu + ((v.u >> 16) & 1u);
  return (unsigned short)(r >> 16);
}

__global__ void fill_f32(float* p, float v, int n){
  int i = blockIdx.x * blockDim.x + threadIdx.x;
  if (i < n) p[i] = v;
}
__global__ void fill_i32(int* p, int v, int n){
  int i = blockIdx.x * blockDim.x + threadIdx.x;
  if (i < n) p[i] = v;
}

// ---------------- tiled register-blocked GEMM ----------------
template<int K, int M, int RT, bool BF16OUT>
__global__ __launch_bounds__((M / 4) * RT) void gemm_tiled(
    const float* __restrict__ A, const float* __restrict__ W,
    const float* __restrict__ bias, void* __restrict__ Cv, int n)
{
  constexpr int CT = M / 4;
  constexpr int BT = CT * RT;
  constexpr int ROWS = 64;
  constexpr int RPT = ROWS / RT;
  constexpr int KP = K + 4;
  __shared__ float ash[ROWS * KP];
  __shared__ float wsh[K * M];

  const int t = threadIdx.x;
  const int row0 = blockIdx.x * ROWS;

  const float4* Wv = (const float4*)W;
  for (int q = t; q < K * M / 4; q += BT)
    *(float4*)&wsh[q * 4] = Wv[q];

  for (int q = t; q < ROWS * K / 4; q += BT){
    int r = q / (K / 4);
    int kq = q - r * (K / 4);
    int grow = row0 + r;
    float4 v = make_float4(0.f, 0.f, 0.f, 0.f);
    if (grow < n) v = *(const float4*)&A[grow * K + kq * 4];
    *(float4*)&ash[r * KP + kq * 4] = v;
  }
  __syncthreads();

  const int c = t % CT;
  const int rt = t / CT;
  const int r0 = rt * RPT;

  float4 bb = make_float4(0.f, 0.f, 0.f, 0.f);
  if (bias) bb = ((const float4*)bias)[c];
  float4 acc[RPT];
  #pragma unroll
  for (int r = 0; r < RPT; ++r) acc[r] = bb;

  for (int k0 = 0; k0 < K; k0 += 4){
    float4 w0 = *(const float4*)&wsh[(k0 + 0) * M + c * 4];
    float4 w1 = *(const float4*)&wsh[(k0 + 1) * M + c * 4];
    float4 w2 = *(const float4*)&wsh[(k0 + 2) * M + c * 4];
    float4 w3 = *(const float4*)&wsh[(k0 + 3) * M + c * 4];
    #pragma unroll
    for (int r = 0; r < RPT; ++r){
      float4 a = *(const float4*)&ash[(r0 + r) * KP + k0];
      acc[r].x += a.x * w0.x + a.y * w1.x + a.z * w2.x + a.w * w3.x;
      acc[r].y += a.x * w0.y + a.y * w1.y + a.z * w2.y + a.w * w3.y;
      acc[r].z += a.x * w0.z + a.y * w1.z + a.z * w2.z + a.w * w3.z;
      acc[r].w += a.x * w0.w + a.y * w1.w + a.z * w2.w + a.w * w3.w;
    }
  }

  #pragma unroll
  for (int r = 0; r < RPT; ++r){
    int row = row0 + r0 + r;
    if (row < n){
      if (BF16OUT){
        ushort4 o;
        o.x = f2bf(acc[r].x); o.y = f2bf(acc[r].y);
        o.z = f2bf(acc[r].z); o.w = f2bf(acc[r].w);
        *(ushort4*)&((unsigned short*)Cv)[row * M + c * 4] = o;
      } else {
        *(float4*)&((float*)Cv)[row * M + c * 4] = acc[r];
      }
    }
  }
}

// el[n,h] = sum_d featl[n,h,d]*al[h,d]; er likewise (featl is bf16)
__global__ void elr_kernel(const unsigned short* __restrict__ featl,
                           const float* __restrict__ al, const float* __restrict__ ar,
                           float* __restrict__ el, float* __restrict__ er,
                           int n, int D){
  int idx = blockIdx.x * blockDim.x + threadIdx.x;
  if (idx >= n * HEADS) return;
  int h = idx & (HEADS - 1);
  const unsigned short* f = featl + (idx >> 2) * (HEADS * D) + h * D;
  float sl = 0.f, sr = 0.f;
  for (int d = 0; d < D; ++d){
    float v = bf2f(f[d]);
    sl += v * al[h * D + d];
    sr += v * ar[h * D + d];
  }
  el[idx] = sl;
  er[idx] = sr;
}

__global__ void residual2_kernel(float* __restrict__ hh, const float* __restrict__ b, int n, int F){
  int idx = blockIdx.x * blockDim.x + threadIdx.x;
  if (idx >= n * F) return;
  int f = idx % F;
  hh[idx] = 2.f * hh[idx] + b[f];
}

// ---------------- CSR build ----------------
__global__ void hist_kernel(const int* __restrict__ dst, int* __restrict__ deg){
  int i = blockIdx.x * blockDim.x + threadIdx.x;
  if (i < N_EDGES) atomicAdd(&deg[dst[i]], 1);
}

// A: per-block partial sums of deg (SCAN_NB blocks x SCAN_B threads)
__global__ __launch_bounds__(SCAN_B) void scan_partials(const int* __restrict__ deg,
                                                        int* __restrict__ part){
  __shared__ int s[SCAN_B];
  int t = threadIdx.x;
  int i = blockIdx.x * SCAN_B + t;
  s[t] = (i < N_NODES) ? deg[i] : 0;
  __syncthreads();
  #pragma unroll
  for (int off = SCAN_B / 2; off; off >>= 1){
    if (t < off) s[t] += s[t + off];
    __syncthreads();
  }
  if (t == 0) part[blockIdx.x] = s[0];
}

// B: exclusive scan of SCAN_NB partials in one block of 512
__global__ __launch_bounds__(512) void scan_offsets(int* __restrict__ part){
  __shared__ int s[512];
  int t = threadIdx.x;
  int v = (t < SCAN_NB) ? part[t] : 0;
  s[t] = v;
  __syncthreads();
  for (int off = 1; off < 512; off <<= 1){
    int u = (t >= off) ? s[t - off] : 0;
    __syncthreads();
    s[t] += u;
    __syncthreads();
  }
  if (t < SCAN_NB) part[t] = s[t] - v;   // exclusive
}

// C: in-block exclusive scan + block offset -> rowptr, cursor
__global__ __launch_bounds__(SCAN_B) void scan_apply(const int* __restrict__ deg,
                                                     const int* __restrict__ part,
                                                     int* __restrict__ rowptr,
                                                     int* __restrict__ cursor){
  __shared__ int s[SCAN_B];
  int t = threadIdx.x;
  int i = blockIdx.x * SCAN_B + t;
  int v = (i < N_NODES) ? deg[i] : 0;
  s[t] = v;
  __syncthreads();
  for (int off = 1; off < SCAN_B; off <<= 1){
    int u = (t >= off) ? s[t - off] : 0;
    __syncthreads();
    s[t] += u;
    __syncthreads();
  }
  if (i < N_NODES){
    int ex = part[blockIdx.x] + s[t] - v;
    rowptr[i] = ex;
    cursor[i] = ex;
  }
  if (i == 0) rowptr[N_NODES] = N_EDGES;
}

__global__ void scatter_kernel(const int* __restrict__ src, const int* __restrict__ dst,
                               int* __restrict__ cursor, int* __restrict__ csr_src){
  int i = blockIdx.x * blockDim.x + threadIdx.x;
  if (i >= N_EDGES) return;
  int d = dst[i];
  int pos = atomicAdd(&cursor[d], 1);
  csr_src[pos] = src[i];
}

// ---------------- per-node softmax + aggregation ----------------
__device__ __forceinline__ float leaky(float x){ return x >= 0.f ? x : NEG_SLOPE * x; }
__device__ __forceinline__ float sel4(float4 v, int h){
  float r = v.x;
  r = (h == 1) ? v.y : r;
  r = (h == 2) ? v.z : r;
  r = (h == 3) ? v.w : r;
  return r;
}

template<int D>
__global__ __launch_bounds__(256) void node_agg_kernel(
    const int* __restrict__ rowptr, const int* __restrict__ csr_src,
    const float* __restrict__ el, const float* __restrict__ er,
    const unsigned short* __restrict__ featl, float* __restrict__ io)
{
  constexpr int F = HEADS * D;
  int wid = threadIdx.x >> 6;
  int lane = threadIdx.x & 63;
  int node = blockIdx.x * 4 + wid;
  if (node >= N_NODES) return;
  int start = rowptr[node], end = rowptr[node + 1];
  int cnt = end - start;
  float4 erd = *(const float4*)(er + 4 * node);

  float m0, m1, m2, m3, s0, s1, s2, s3;
  if (cnt <= 64){
    float x0 = -1e30f, x1 = -1e30f, x2 = -1e30f, x3 = -1e30f;
    if (lane < cnt){
      int s = csr_src[start + lane];
      float4 e4 = *(const float4*)(el + 4 * s);
      x0 = leaky(e4.x + erd.x); x1 = leaky(e4.y + erd.y);
      x2 = leaky(e4.z + erd.z); x3 = leaky(e4.w + erd.w);
    }
    m0 = x0; m1 = x1; m2 = x2; m3 = x3;
    #pragma unroll
    for (int off = 32; off; off >>= 1){
      m0 = fmaxf(m0, __shfl_xor(m0, off, 64));
      m1 = fmaxf(m1, __shfl_xor(m1, off, 64));
      m2 = fmaxf(m2, __shfl_xor(m2, off, 64));
      m3 = fmaxf(m3, __shfl_xor(m3, off, 64));
    }
    float e0 = 0.f, e1 = 0.f, e2 = 0.f, e3 = 0.f;
    if (lane < cnt){
      e0 = __expf(x0 - m0); e1 = __expf(x1 - m1);
      e2 = __expf(x2 - m2); e3 = __expf(x3 - m3);
    }
    s0 = e0; s1 = e1; s2 = e2; s3 = e3;
    #pragma unroll
    for (int off = 32; off; off >>= 1){
      s0 += __shfl_xor(s0, off, 64);
      s1 += __shfl_xor(s1, off, 64);
      s2 += __shfl_xor(s2, off, 64);
      s3 += __shfl_xor(s3, off, 64);
    }
  } else {
    m0 = -1e30f; m1 = -1e30f; m2 = -1e30f; m3 = -1e30f;
    for (int i = start + lane; i < end; i += 64){
      int s = csr_src[i];
      float4 e4 = *(const float4*)(el + 4 * s);
      m0 = fmaxf(m0, leaky(e4.x + erd.x));
      m1 = fmaxf(m1, leaky(e4.y + erd.y));
      m2 = fmaxf(m2, leaky(e4.z + erd.z));
      m3 = fmaxf(m3, leaky(e4.w + erd.w));
    }
    #pragma unroll
    for (int off = 32; off; off >>= 1){
      m0 = fmaxf(m0, __shfl_xor(m0, off, 64));
      m1 = fmaxf(m1, __shfl_xor(m1, off, 64));
      m2 = fmaxf(m2, __shfl_xor(m2, off, 64));
      m3 = fmaxf(m3, __shfl_xor(m3, off, 64));
    }
    s0 = 0.f; s1 = 0.f; s2 = 0.f; s3 = 0.f;
    for (int i = start + lane; i < end; i += 64){
      int s = csr_src[i];
      float4 e4 = *(const float4*)(el + 4 * s);
      s0 += __expf(leaky(e4.x + erd.x) - m0);
      s1 += __expf(leaky(e4.y + erd.y) - m1);
      s2 += __expf(leaky(e4.z + erd.z) - m2);
      s3 += __expf(leaky(e4.w + erd.w) - m3);
    }
    #pragma unroll
    for (int off = 32; off; off >>= 1){
      s0 += __shfl_xor(s0, off, 64);
      s1 += __shfl_xor(s1, off, 64);
      s2 += __shfl_xor(s2, off, 64);
      s3 += __shfl_xor(s3, off, 64);
    }
  }
  float4 mh = make_float4(m0, m1, m2, m3);
  float4 ih = make_float4(1.f / fmaxf(s0, 1e-16f), 1.f / fmaxf(s1, 1e-16f),
                          1.f / fmaxf(s2, 1e-16f), 1.f / fmaxf(s3, 1e-16f));

  const int f0 = lane;
  const int h0 = f0 / D;
  const float er0 = sel4(erd, h0), mm0 = sel4(mh, h0), ii0 = sel4(ih, h0);
  float acc0 = io[node * F + f0];
  const unsigned short* fb = featl + f0;

  if (D == 16){
    int i = start;
    int e4i = start + (cnt & ~3);
    for (; i < e4i; i += 4){
      int sA = csr_src[i], sB = csr_src[i + 1], sC = csr_src[i + 2], sD = csr_src[i + 3];
      float4 eA = *(const float4*)(el + 4 * sA);
      float4 eB = *(const float4*)(el + 4 * sB);
      float4 eC = *(const float4*)(el + 4 * sC);
      float4 eD = *(const float4*)(el + 4 * sD);
      float fA = bf2f(fb[sA * F]);
      float fB = bf2f(fb[sB * F]);
      float fC = bf2f(fb[sC * F]);
      float fD = bf2f(fb[sD * F]);
      acc0 += __expf(leaky(sel4(eA, h0) + er0) - mm0) * ii0 * fA;
      acc0 += __expf(leaky(sel4(eB, h0) + er0) - mm0) * ii0 * fB;
      acc0 += __expf(leaky(sel4(eC, h0) + er0) - mm0) * ii0 * fC;
      acc0 += __expf(leaky(sel4(eD, h0) + er0) - mm0) * ii0 * fD;
    }
    for (; i < end; ++i){
      int s = csr_src[i];
      float4 e4 = *(const float4*)(el + 4 * s);
      acc0 += __expf(leaky(sel4(e4, h0) + er0) - mm0) * ii0 * bf2f(fb[s * F]);
    }
    io[node * F + f0] = acc0;
  } else {
    const int h1 = (lane + 64) / D;
    const int h2 = 3;
    const float er1 = sel4(erd, h1), mm1 = sel4(mh, h1), ii1 = sel4(ih, h1);
    const float er2 = sel4(erd, h2), mm2 = sel4(mh, h2), ii2 = sel4(ih, h2);
    float acc1 = io[node * F + lane + 64];
    float acc2 = (lane < F - 128) ? io[node * F + lane + 128] : 0.f;
    int i = start;
    int e2i = start + (cnt & ~1);
    for (; i < e2i; i += 2){
      int sA = csr_src[i], sB = csr_src[i + 1];
      float4 eA = *(const float4*)(el + 4 * sA);
      float4 eB = *(const float4*)(el + 4 * sB);
      float fA0 = bf2f(fb[sA * F]);
      float fA1 = bf2f(fb[sA * F + 64]);
      float fA2 = (lane < F - 128) ? bf2f(fb[sA * F + 128]) : 0.f;
      float fB0 = bf2f(fb[sB * F]);
      float fB1 = bf2f(fb[sB * F + 64]);
      float fB2 = (lane < F - 128) ? bf2f(fb[sB * F + 128]) : 0.f;
      acc0 += __expf(leaky(sel4(eA, h0) + er0) - mm0) * ii0 * fA0;
      acc1 += __expf(leaky(sel4(eA, h1) + er1) - mm1) * ii1 * fA1;
      acc2 += __expf(leaky(sel4(eA, h2) + er2) - mm2) * ii2 * fA2;
      acc0 += __expf(leaky(sel4(eB, h0) + er0) - mm0) * ii0 * fB0;
      acc1 += __expf(leaky(sel4(eB, h1) + er1) - mm1) * ii1 * fB1;
      acc2 += __expf(leaky(sel4(eB, h2) + er2) - mm2) * ii2 * fB2;
    }
    for (; i < end; ++i){
      int s = csr_src[i];
      float4 e4 = *(const float4*)(el + 4 * s);
      acc0 += __expf(leaky(sel4(e4, h0) + er0) - mm0) * ii0 * bf2f(fb[s * F]);
      acc1 += __expf(leaky(sel4(e4, h1) + er1) - mm1) * ii1 * bf2f(fb[s * F + 64]);
      if (lane < F - 128)
        acc2 += __expf(leaky(sel4(e4, h2) + er2) - mm2) * ii2 * bf2f(fb[s * F + 128]);
    }
    io[node * F + f0] = acc0;
    io[node * F + lane + 64] = acc1;
    if (lane < F - 128) io[node * F + lane + 128] = acc2;
  }
}

// ---------------- BatchNorm ----------------
__global__ void bn_stats_kernel(const float* __restrict__ x, float* __restrict__ sums, int n){
  __shared__ float s[512];
  int tid = threadIdx.x;
  int f = tid & 63, g = tid >> 6;
  float sm = 0.f, sq = 0.f;
  for (int r = blockIdx.x * 4 + g; r < n; r += gridDim.x * 4){
    float v = x[r * 64 + f];
    sm += v; sq += v * v;
  }
  s[tid] = sm; s[256 + tid] = sq;
  __syncthreads();
  if (g == 0){
    float a = s[f] + s[64 + f] + s[128 + f] + s[192 + f];
    float b = s[256 + f] + s[320 + f] + s[384 + f] + s[448 + f];
    atomicAdd(&sums[f], a);
    atomicAdd(&sums[64 + f], b);
  }
}

__global__ void bn_finalize_kernel(float* __restrict__ stats, int n){
  int f = threadIdx.x;
  if (f < 64){
    float mu = stats[f] / n;
    float var = stats[64 + f] / n - mu * mu;
    stats[128 + f] = mu;
    stats[192 + f] = rsqrtf(var + BN_EPS);
  }
}

__global__ void bn_apply_kernel(float* __restrict__ x, const float* __restrict__ stats,
                                const float* __restrict__ gamma, const float* __restrict__ beta,
                                int n){
  int idx = blockIdx.x * blockDim.x + threadIdx.x;
  if (idx >= n * 64) return;
  int f = idx & 63;
  float v = (x[idx] - stats[128 + f]) * stats[192 + f] * gamma[f] + beta[f];
  x[idx] = v > 0.f ? v : 0.f;
}

extern "C" void kernel_launch(void* const* d_in, const int* in_sizes, int n_in,
                              void* d_out, int out_size, void* d_ws, size_t ws_size,
                              hipStream_t stream){
  const float* feat  = (const float*)d_in[0];
  const int*   src   = (const int*)d_in[1];
  const int*   dst   = (const int*)d_in[2];
  const float* W0    = (const float*)d_in[3];
  const float* al0   = (const float*)d_in[4];
  const float* ar0   = (const float*)d_in[5];
  const float* b0    = (const float*)d_in[6];
  const float* resW0 = (const float*)d_in[7];
  const float* g0    = (const float*)d_in[8];
  const float* be0   = (const float*)d_in[9];
  const float* W1    = (const float*)d_in[10];
  const float* al1   = (const float*)d_in[11];
  const float* ar1   = (const float*)d_in[12];
  const float* b1    = (const float*)d_in[13];
  const float* g1    = (const float*)d_in[14];
  const float* be1   = (const float*)d_in[15];
  const float* W2    = (const float*)d_in[16];
  const float* al2   = (const float*)d_in[17];
  const float* ar2   = (const float*)d_in[18];
  const float* b2    = (const float*)d_in[19];
  const float* resW2 = (const float*)d_in[20];
  float* out = (float*)d_out;

  unsigned short* featl = (unsigned short*)d_ws;          // N*160 bf16
  float* h     = (float*)(featl + N_NODES * 160);         // N*64 f32
  float* el    = h + N_NODES * 64;                        // N*4
  float* er    = el + N_NODES * 4;                        // N*4
  float* stats = er + N_NODES * 4;                        // 256
  int* rowptr  = (int*)(stats + 256);                     // N+1
  int* cursor  = rowptr + (N_NODES + 1);                  // N
  int* deg     = cursor + N_NODES;                        // N
  int* part    = deg + N_NODES;                           // SCAN_NB
  int* csr_src = part + SCAN_NB + 1;                      // E

  const int B = 256;
  const int gNH  = cdiv(N_NODES * HEADS, B);
  const int gE   = cdiv(N_EDGES, B);
  const int g64  = cdiv(N_NODES * 64, B);
  const int gN   = cdiv(N_NODES, B);
  const int gAgg = cdiv(N_NODES, 4);
  const int gGemm = cdiv(N_NODES, 64);

  // ---------- CSR build (reused by all 3 layers) ----------
  fill_i32<<<gN, B, 0, stream>>>(deg, 0, N_NODES);
  hist_kernel<<<gE, B, 0, stream>>>(dst, deg);
  scan_partials<<<SCAN_NB, SCAN_B, 0, stream>>>(deg, part);
  scan_offsets<<<1, 512, 0, stream>>>(part);
  scan_apply<<<SCAN_NB, SCAN_B, 0, stream>>>(deg, part, rowptr, cursor);
  scatter_kernel<<<gE, B, 0, stream>>>(src, dst, cursor, csr_src);

  // ================= layer 0 =================
  gemm_tiled<128, 64, 16, true><<<gGemm, 256, 0, stream>>>(feat, W0, nullptr, featl, N_NODES);
  elr_kernel<<<gNH, B, 0, stream>>>(featl, al0, ar0, el, er, N_NODES, HID);
  gemm_tiled<128, 64, 16, false><<<gGemm, 256, 0, stream>>>(feat, resW0, b0, h, N_NODES);
  node_agg_kernel<HID><<<gAgg, 256, 0, stream>>>(rowptr, csr_src, el, er, featl, h);
  fill_f32<<<1, 128, 0, stream>>>(stats, 0.f, 128);
  bn_stats_kernel<<<512, 256, 0, stream>>>(h, stats, N_NODES);
  bn_finalize_kernel<<<1, 64, 0, stream>>>(stats, N_NODES);
  bn_apply_kernel<<<g64, B, 0, stream>>>(h, stats, g0, be0, N_NODES);

  // ================= layer 1 =================
  gemm_tiled<64, 64, 16, true><<<gGemm, 256, 0, stream>>>(h, W1, nullptr, featl, N_NODES);
  elr_kernel<<<gNH, B, 0, stream>>>(featl, al1, ar1, el, er, N_NODES, HID);
  residual2_kernel<<<g64, B, 0, stream>>>(h, b1, N_NODES, 64);
  node_agg_kernel<HID><<<gAgg, 256, 0, stream>>>(rowptr, csr_src, el, er, featl, h);
  fill_f32<<<1, 128, 0, stream>>>(stats, 0.f, 128);
  bn_stats_kernel<<<512, 256, 0, stream>>>(h, stats, N_NODES);
  bn_finalize_kernel<<<1, 64, 0, stream>>>(stats, N_NODES);
  bn_apply_kernel<<<g64, B, 0, stream>>>(h, stats, g1, be1, N_NODES);

  // ================= layer 2 =================
  gemm_tiled<64, 160, 8, true><<<gGemm, 320, 0, stream>>>(h, W2, nullptr, featl, N_NODES);
  elr_kernel<<<gNH, B, 0, stream>>>(featl, al2, ar2, el, er, N_NODES, OUTC);
  gemm_tiled<64, 160, 8, false><<<gGemm, 320, 0, stream>>>(h, resW2, b2, out, N_NODES);
  node_agg_kernel<OUTC><<<gAgg, 256, 0, stream>>>(rowptr, csr_src, el, er, featl, out);
}

// Round 6
// 1002.478 us; speedup vs baseline: 26.1783x; 1.1403x over previous
//
#include <hip/hip_runtime.h>
#include <cstdint>

#define N_NODES 100000
#define N_EDGES 1600000
#define F_IN 128
#define HID 16
#define HEADS 4
#define OUTC 40
#define NEG_SLOPE 0.2f
#define BN_EPS 1e-5f

#define SCAN_B 256
#define SCAN_NB ((N_NODES + SCAN_B - 1) / SCAN_B)   // 391

static inline int cdiv(int a, int b){ return (a + b - 1) / b; }

__device__ __forceinline__ float bf2f(unsigned short u){
  union { unsigned u32; float f; } v; v.u32 = ((unsigned)u) << 16; return v.f;
}
__device__ __forceinline__ unsigned short f2bf(float x){
  union { float f; unsigned u; } v; v.f = x;
  unsigned r = v.u + 0x7FFFu + ((v.u >> 16) & 1u);
  return (unsigned short)(r >> 16);
}

__global__ void fill_f32(float* p, float v, int n){
  int i = blockIdx.x * blockDim.x + threadIdx.x;
  if (i < n) p[i] = v;
}
__global__ void fill_i32(int* p, int v, int n){
  int i = blockIdx.x * blockDim.x + threadIdx.x;
  if (i < n) p[i] = v;
}

// ---------------- tiled register-blocked GEMM ----------------
template<int K, int M, int RT, bool BF16OUT>
__global__ __launch_bounds__((M / 4) * RT) void gemm_tiled(
    const float* __restrict__ A, const float* __restrict__ W,
    const float* __restrict__ bias, void* __restrict__ Cv, int n)
{
  constexpr int CT = M / 4;
  constexpr int BT = CT * RT;
  constexpr int ROWS = 64;
  constexpr int RPT = ROWS / RT;
  constexpr int KP = K + 4;
  __shared__ float ash[ROWS * KP];
  __shared__ float wsh[K * M];

  const int t = threadIdx.x;
  const int row0 = blockIdx.x * ROWS;

  const float4* Wv = (const float4*)W;
  for (int q = t; q < K * M / 4; q += BT)
    *(float4*)&wsh[q * 4] = Wv[q];

  for (int q = t; q < ROWS * K / 4; q += BT){
    int r = q / (K / 4);
    int kq = q - r * (K / 4);
    int grow = row0 + r;
    float4 v = make_float4(0.f, 0.f, 0.f, 0.f);
    if (grow < n) v = *(const float4*)&A[grow * K + kq * 4];
    *(float4*)&ash[r * KP + kq * 4] = v;
  }
  __syncthreads();

  const int c = t % CT;
  const int rt = t / CT;
  const int r0 = rt * RPT;

  float4 bb = make_float4(0.f, 0.f, 0.f, 0.f);
  if (bias) bb = ((const float4*)bias)[c];
  float4 acc[RPT];
  #pragma unroll
  for (int r = 0; r < RPT; ++r) acc[r] = bb;

  for (int k0 = 0; k0 < K; k0 += 4){
    float4 w0 = *(const float4*)&wsh[(k0 + 0) * M + c * 4];
    float4 w1 = *(const float4*)&wsh[(k0 + 1) * M + c * 4];
    float4 w2 = *(const float4*)&wsh[(k0 + 2) * M + c * 4];
    float4 w3 = *(const float4*)&wsh[(k0 + 3) * M + c * 4];
    #pragma unroll
    for (int r = 0; r < RPT; ++r){
      float4 a = *(const float4*)&ash[(r0 + r) * KP + k0];
      acc[r].x += a.x * w0.x + a.y * w1.x + a.z * w2.x + a.w * w3.x;
      acc[r].y += a.x * w0.y + a.y * w1.y + a.z * w2.y + a.w * w3.y;
      acc[r].z += a.x * w0.z + a.y * w1.z + a.z * w2.z + a.w * w3.z;
      acc[r].w += a.x * w0.w + a.y * w1.w + a.z * w2.w + a.w * w3.w;
    }
  }

  #pragma unroll
  for (int r = 0; r < RPT; ++r){
    int row = row0 + r0 + r;
    if (row < n){
      if (BF16OUT){
        ushort4 o;
        o.x = f2bf(acc[r].x); o.y = f2bf(acc[r].y);
        o.z = f2bf(acc[r].z); o.w = f2bf(acc[r].w);
        *(ushort4*)&((unsigned short*)Cv)[row * M + c * 4] = o;
      } else {
        *(float4*)&((float*)Cv)[row * M + c * 4] = acc[r];
      }
    }
  }
}

// el[n,h] = sum_d featl[n,h,d]*al[h,d]; er likewise (featl is bf16)
__global__ void elr_kernel(const unsigned short* __restrict__ featl,
                           const float* __restrict__ al, const float* __restrict__ ar,
                           float* __restrict__ el, float* __restrict__ er,
                           int n, int D){
  int idx = blockIdx.x * blockDim.x + threadIdx.x;
  if (idx >= n * HEADS) return;
  int h = idx & (HEADS - 1);
  const unsigned short* f = featl + (idx >> 2) * (HEADS * D) + h * D;
  float sl = 0.f, sr = 0.f;
  for (int d = 0; d < D; ++d){
    float v = bf2f(f[d]);
    sl += v * al[h * D + d];
    sr += v * ar[h * D + d];
  }
  el[idx] = sl;
  er[idx] = sr;
}

__global__ void residual2_kernel(float* __restrict__ hh, const float* __restrict__ b, int n, int F){
  int idx = blockIdx.x * blockDim.x + threadIdx.x;
  if (idx >= n * F) return;
  int f = idx % F;
  hh[idx] = 2.f * hh[idx] + b[f];
}

// ---------------- CSR build ----------------
__global__ void hist_kernel(const int* __restrict__ dst, int* __restrict__ deg){
  int i = blockIdx.x * blockDim.x + threadIdx.x;
  if (i < N_EDGES) atomicAdd(&deg[dst[i]], 1);
}

__global__ __launch_bounds__(SCAN_B) void scan_partials(const int* __restrict__ deg,
                                                        int* __restrict__ part){
  __shared__ int s[SCAN_B];
  int t = threadIdx.x;
  int i = blockIdx.x * SCAN_B + t;
  s[t] = (i < N_NODES) ? deg[i] : 0;
  __syncthreads();
  #pragma unroll
  for (int off = SCAN_B / 2; off; off >>= 1){
    if (t < off) s[t] += s[t + off];
    __syncthreads();
  }
  if (t == 0) part[blockIdx.x] = s[0];
}

__global__ __launch_bounds__(512) void scan_offsets(int* __restrict__ part){
  __shared__ int s[512];
  int t = threadIdx.x;
  int v = (t < SCAN_NB) ? part[t] : 0;
  s[t] = v;
  __syncthreads();
  for (int off = 1; off < 512; off <<= 1){
    int u = (t >= off) ? s[t - off] : 0;
    __syncthreads();
    s[t] += u;
    __syncthreads();
  }
  if (t < SCAN_NB) part[t] = s[t] - v;   // exclusive
}

__global__ __launch_bounds__(SCAN_B) void scan_apply(const int* __restrict__ deg,
                                                     const int* __restrict__ part,
                                                     int* __restrict__ rowptr,
                                                     int* __restrict__ cursor){
  __shared__ int s[SCAN_B];
  int t = threadIdx.x;
  int i = blockIdx.x * SCAN_B + t;
  int v = (i < N_NODES) ? deg[i] : 0;
  s[t] = v;
  __syncthreads();
  for (int off = 1; off < SCAN_B; off <<= 1){
    int u = (t >= off) ? s[t - off] : 0;
    __syncthreads();
    s[t] += u;
    __syncthreads();
  }
  if (i < N_NODES){
    int ex = part[blockIdx.x] + s[t] - v;
    rowptr[i] = ex;
    cursor[i] = ex;
  }
  if (i == 0) rowptr[N_NODES] = N_EDGES;
}

__global__ void scatter_kernel(const int* __restrict__ src, const int* __restrict__ dst,
                               int* __restrict__ cursor, int* __restrict__ csr_src){
  int i = blockIdx.x * blockDim.x + threadIdx.x;
  if (i >= N_EDGES) return;
  int d = dst[i];
  int pos = atomicAdd(&cursor[d], 1);
  csr_src[pos] = src[i];
}

// ---------------- per-node softmax + aggregation ----------------
__device__ __forceinline__ float leaky(float x){ return x >= 0.f ? x : NEG_SLOPE * x; }
__device__ __forceinline__ float sel4(float4 v, int h){
  float r = v.x;
  r = (h == 1) ? v.y : r;
  r = (h == 2) ? v.z : r;
  r = (h == 3) ? v.w : r;
  return r;
}

// One wave per node. Fast path (deg<=64): per-edge normalized alpha (4 heads)
// and cached src index stored in LDS by pass 1; pass 2 is 1 ds_read + 1 gather
// + 1 FMA per (edge, feature-lane) — no exp recompute.
template<int D>
__global__ __launch_bounds__(256) void node_agg_kernel(
    const int* __restrict__ rowptr, const int* __restrict__ csr_src,
    const float* __restrict__ el, const float* __restrict__ er,
    const unsigned short* __restrict__ featl, float* __restrict__ io)
{
  constexpr int F = HEADS * D;
  __shared__ float alds[4][64][4];   // per-edge alpha (4 heads)
  __shared__ int   slds[4][64];      // per-edge src index
  int wid = threadIdx.x >> 6;
  int lane = threadIdx.x & 63;
  int node = blockIdx.x * 4 + wid;
  if (node >= N_NODES) return;
  int start = rowptr[node], end = rowptr[node + 1];
  int cnt = end - start;
  float4 erd = *(const float4*)(er + 4 * node);
  bool fast = (cnt <= 64);

  float4 mh, ih;
  if (fast){
    int sidx = 0;
    float x0 = -1e30f, x1 = -1e30f, x2 = -1e30f, x3 = -1e30f;
    if (lane < cnt){
      sidx = csr_src[start + lane];
      float4 e4 = *(const float4*)(el + 4 * sidx);
      x0 = leaky(e4.x + erd.x); x1 = leaky(e4.y + erd.y);
      x2 = leaky(e4.z + erd.z); x3 = leaky(e4.w + erd.w);
    }
    float m0 = x0, m1 = x1, m2 = x2, m3 = x3;
    #pragma unroll
    for (int off = 32; off; off >>= 1){
      m0 = fmaxf(m0, __shfl_xor(m0, off, 64));
      m1 = fmaxf(m1, __shfl_xor(m1, off, 64));
      m2 = fmaxf(m2, __shfl_xor(m2, off, 64));
      m3 = fmaxf(m3, __shfl_xor(m3, off, 64));
    }
    float e0 = 0.f, e1 = 0.f, e2 = 0.f, e3 = 0.f;
    if (lane < cnt){
      e0 = __expf(x0 - m0); e1 = __expf(x1 - m1);
      e2 = __expf(x2 - m2); e3 = __expf(x3 - m3);
    }
    float s0 = e0, s1 = e1, s2 = e2, s3 = e3;
    #pragma unroll
    for (int off = 32; off; off >>= 1){
      s0 += __shfl_xor(s0, off, 64);
      s1 += __shfl_xor(s1, off, 64);
      s2 += __shfl_xor(s2, off, 64);
      s3 += __shfl_xor(s3, off, 64);
    }
    ih = make_float4(1.f / fmaxf(s0, 1e-16f), 1.f / fmaxf(s1, 1e-16f),
                     1.f / fmaxf(s2, 1e-16f), 1.f / fmaxf(s3, 1e-16f));
    if (lane < cnt){
      slds[wid][lane] = sidx;
      float4 av = make_float4(e0 * ih.x, e1 * ih.y, e2 * ih.z, e3 * ih.w);
      *(float4*)&alds[wid][lane][0] = av;
    }
    // same-wave LDS write->read: DS ops of a wave complete in order; no barrier.
  } else {
    float m0 = -1e30f, m1 = -1e30f, m2 = -1e30f, m3 = -1e30f;
    for (int i = start + lane; i < end; i += 64){
      int s = csr_src[i];
      float4 e4 = *(const float4*)(el + 4 * s);
      m0 = fmaxf(m0, leaky(e4.x + erd.x));
      m1 = fmaxf(m1, leaky(e4.y + erd.y));
      m2 = fmaxf(m2, leaky(e4.z + erd.z));
      m3 = fmaxf(m3, leaky(e4.w + erd.w));
    }
    #pragma unroll
    for (int off = 32; off; off >>= 1){
      m0 = fmaxf(m0, __shfl_xor(m0, off, 64));
      m1 = fmaxf(m1, __shfl_xor(m1, off, 64));
      m2 = fmaxf(m2, __shfl_xor(m2, off, 64));
      m3 = fmaxf(m3, __shfl_xor(m3, off, 64));
    }
    float s0 = 0.f, s1 = 0.f, s2 = 0.f, s3 = 0.f;
    for (int i = start + lane; i < end; i += 64){
      int s = csr_src[i];
      float4 e4 = *(const float4*)(el + 4 * s);
      s0 += __expf(leaky(e4.x + erd.x) - m0);
      s1 += __expf(leaky(e4.y + erd.y) - m1);
      s2 += __expf(leaky(e4.z + erd.z) - m2);
      s3 += __expf(leaky(e4.w + erd.w) - m3);
    }
    #pragma unroll
    for (int off = 32; off; off >>= 1){
      s0 += __shfl_xor(s0, off, 64);
      s1 += __shfl_xor(s1, off, 64);
      s2 += __shfl_xor(s2, off, 64);
      s3 += __shfl_xor(s3, off, 64);
    }
    mh = make_float4(m0, m1, m2, m3);
    ih = make_float4(1.f / fmaxf(s0, 1e-16f), 1.f / fmaxf(s1, 1e-16f),
                     1.f / fmaxf(s2, 1e-16f), 1.f / fmaxf(s3, 1e-16f));
  }

  const int f0 = lane;
  const int h0 = f0 / D;
  float acc0 = io[node * F + f0];
  const unsigned short* fb = featl + f0;

  if (D == 16){
    if (fast){
      const float* ap = &alds[wid][0][h0];
      const int* sp = &slds[wid][0];
      int j = 0;
      for (; j + 3 < cnt; j += 4){
        int sA = sp[j], sB = sp[j + 1], sC = sp[j + 2], sD = sp[j + 3];
        float aA = ap[4 * j], aB = ap[4 * (j + 1)], aC = ap[4 * (j + 2)], aD = ap[4 * (j + 3)];
        acc0 += aA * bf2f(fb[sA * F]);
        acc0 += aB * bf2f(fb[sB * F]);
        acc0 += aC * bf2f(fb[sC * F]);
        acc0 += aD * bf2f(fb[sD * F]);
      }
      for (; j < cnt; ++j)
        acc0 += ap[4 * j] * bf2f(fb[sp[j] * F]);
    } else {
      const float er0 = sel4(erd, h0), mm0 = sel4(mh, h0), ii0 = sel4(ih, h0);
      for (int i = start; i < end; ++i){
        int s = csr_src[i];
        float4 e4 = *(const float4*)(el + 4 * s);
        acc0 += __expf(leaky(sel4(e4, h0) + er0) - mm0) * ii0 * bf2f(fb[s * F]);
      }
    }
    io[node * F + f0] = acc0;
  } else {
    const int h1 = (lane + 64) / D;
    const int h2 = 3;
    float acc1 = io[node * F + lane + 64];
    float acc2 = (lane < F - 128) ? io[node * F + lane + 128] : 0.f;
    if (fast){
      const float* ab = &alds[wid][0][0];
      const int* sp = &slds[wid][0];
      int j = 0;
      for (; j + 1 < cnt; j += 2){
        int sA = sp[j], sB = sp[j + 1];
        float aA0 = ab[4 * j + h0], aA1 = ab[4 * j + h1], aA2 = ab[4 * j + h2];
        float aB0 = ab[4 * (j + 1) + h0], aB1 = ab[4 * (j + 1) + h1], aB2 = ab[4 * (j + 1) + h2];
        acc0 += aA0 * bf2f(fb[sA * F]);
        acc1 += aA1 * bf2f(fb[sA * F + 64]);
        acc0 += aB0 * bf2f(fb[sB * F]);
        acc1 += aB1 * bf2f(fb[sB * F + 64]);
        if (lane < F - 128){
          acc2 += aA2 * bf2f(fb[sA * F + 128]);
          acc2 += aB2 * bf2f(fb[sB * F + 128]);
        }
      }
      for (; j < cnt; ++j){
        int s = sp[j];
        acc0 += ab[4 * j + h0] * bf2f(fb[s * F]);
        acc1 += ab[4 * j + h1] * bf2f(fb[s * F + 64]);
        if (lane < F - 128) acc2 += ab[4 * j + h2] * bf2f(fb[s * F + 128]);
      }
    } else {
      const float er0 = sel4(erd, h0), mm0 = sel4(mh, h0), ii0 = sel4(ih, h0);
      const float er1 = sel4(erd, h1), mm1 = sel4(mh, h1), ii1 = sel4(ih, h1);
      const float er2 = sel4(erd, h2), mm2 = sel4(mh, h2), ii2 = sel4(ih, h2);
      for (int i = start; i < end; ++i){
        int s = csr_src[i];
        float4 e4 = *(const float4*)(el + 4 * s);
        acc0 += __expf(leaky(sel4(e4, h0) + er0) - mm0) * ii0 * bf2f(fb[s * F]);
        acc1 += __expf(leaky(sel4(e4, h1) + er1) - mm1) * ii1 * bf2f(fb[s * F + 64]);
        if (lane < F - 128)
          acc2 += __expf(leaky(sel4(e4, h2) + er2) - mm2) * ii2 * bf2f(fb[s * F + 128]);
      }
    }
    io[node * F + f0] = acc0;
    io[node * F + lane + 64] = acc1;
    if (lane < F - 128) io[node * F + lane + 128] = acc2;
  }
}

// ---------------- BatchNorm ----------------
__global__ void bn_stats_kernel(const float* __restrict__ x, float* __restrict__ sums, int n){
  __shared__ float s[512];
  int tid = threadIdx.x;
  int f = tid & 63, g = tid >> 6;
  float sm = 0.f, sq = 0.f;
  for (int r = blockIdx.x * 4 + g; r < n; r += gridDim.x * 4){
    float v = x[r * 64 + f];
    sm += v; sq += v * v;
  }
  s[tid] = sm; s[256 + tid] = sq;
  __syncthreads();
  if (g == 0){
    float a = s[f] + s[64 + f] + s[128 + f] + s[192 + f];
    float b = s[256 + f] + s[320 + f] + s[384 + f] + s[448 + f];
    atomicAdd(&sums[f], a);
    atomicAdd(&sums[64 + f], b);
  }
}

__global__ void bn_finalize_kernel(float* __restrict__ stats, int n){
  int f = threadIdx.x;
  if (f < 64){
    float mu = stats[f] / n;
    float var = stats[64 + f] / n - mu * mu;
    stats[128 + f] = mu;
    stats[192 + f] = rsqrtf(var + BN_EPS);
  }
}

__global__ void bn_apply_kernel(float* __restrict__ x, const float* __restrict__ stats,
                                const float* __restrict__ gamma, const float* __restrict__ beta,
                                int n){
  int idx = blockIdx.x * blockDim.x + threadIdx.x;
  if (idx >= n * 64) return;
  int f = idx & 63;
  float v = (x[idx] - stats[128 + f]) * stats[192 + f] * gamma[f] + beta[f];
  x[idx] = v > 0.f ? v : 0.f;
}

extern "C" void kernel_launch(void* const* d_in, const int* in_sizes, int n_in,
                              void* d_out, int out_size, void* d_ws, size_t ws_size,
                              hipStream_t stream){
  const float* feat  = (const float*)d_in[0];
  const int*   src   = (const int*)d_in[1];
  const int*   dst   = (const int*)d_in[2];
  const float* W0    = (const float*)d_in[3];
  const float* al0   = (const float*)d_in[4];
  const float* ar0   = (const float*)d_in[5];
  const float* b0    = (const float*)d_in[6];
  const float* resW0 = (const float*)d_in[7];
  const float* g0    = (const float*)d_in[8];
  const float* be0   = (const float*)d_in[9];
  const float* W1    = (const float*)d_in[10];
  const float* al1   = (const float*)d_in[11];
  const float* ar1   = (const float*)d_in[12];
  const float* b1    = (const float*)d_in[13];
  const float* g1    = (const float*)d_in[14];
  const float* be1   = (const float*)d_in[15];
  const float* W2    = (const float*)d_in[16];
  const float* al2   = (const float*)d_in[17];
  const float* ar2   = (const float*)d_in[18];
  const float* b2    = (const float*)d_in[19];
  const float* resW2 = (const float*)d_in[20];
  float* out = (float*)d_out;

  unsigned short* featl = (unsigned short*)d_ws;          // N*160 bf16
  float* h     = (float*)(featl + N_NODES * 160);         // N*64 f32
  float* el    = h + N_NODES * 64;                        // N*4
  float* er    = el + N_NODES * 4;                        // N*4
  float* stats = er + N_NODES * 4;                        // 256
  int* rowptr  = (int*)(stats + 256);                     // N+1
  int* cursor  = rowptr + (N_NODES + 1);                  // N
  int* deg     = cursor + N_NODES;                        // N
  int* part    = deg + N_NODES;                           // SCAN_NB
  int* csr_src = part + SCAN_NB + 1;                      // E

  const int B = 256;
  const int gNH  = cdiv(N_NODES * HEADS, B);
  const int gE   = cdiv(N_EDGES, B);
  const int g64  = cdiv(N_NODES * 64, B);
  const int gN   = cdiv(N_NODES, B);
  const int gAgg = cdiv(N_NODES, 4);
  const int gGemm = cdiv(N_NODES, 64);

  // ---------- CSR build (reused by all 3 layers) ----------
  fill_i32<<<gN, B, 0, stream>>>(deg, 0, N_NODES);
  hist_kernel<<<gE, B, 0, stream>>>(dst, deg);
  scan_partials<<<SCAN_NB, SCAN_B, 0, stream>>>(deg, part);
  scan_offsets<<<1, 512, 0, stream>>>(part);
  scan_apply<<<SCAN_NB, SCAN_B, 0, stream>>>(deg, part, rowptr, cursor);
  scatter_kernel<<<gE, B, 0, stream>>>(src, dst, cursor, csr_src);

  // ================= layer 0 =================
  gemm_tiled<128, 64, 16, true><<<gGemm, 256, 0, stream>>>(feat, W0, nullptr, featl, N_NODES);
  elr_kernel<<<gNH, B, 0, stream>>>(featl, al0, ar0, el, er, N_NODES, HID);
  gemm_tiled<128, 64, 16, false><<<gGemm, 256, 0, stream>>>(feat, resW0, b0, h, N_NODES);
  node_agg_kernel<HID><<<gAgg, 256, 0, stream>>>(rowptr, csr_src, el, er, featl, h);
  fill_f32<<<1, 128, 0, stream>>>(stats, 0.f, 128);
  bn_stats_kernel<<<512, 256, 0, stream>>>(h, stats, N_NODES);
  bn_finalize_kernel<<<1, 64, 0, stream>>>(stats, N_NODES);
  bn_apply_kernel<<<g64, B, 0, stream>>>(h, stats, g0, be0, N_NODES);

  // ================= layer 1 =================
  gemm_tiled<64, 64, 16, true><<<gGemm, 256, 0, stream>>>(h, W1, nullptr, featl, N_NODES);
  elr_kernel<<<gNH, B, 0, stream>>>(featl, al1, ar1, el, er, N_NODES, HID);
  residual2_kernel<<<g64, B, 0, stream>>>(h, b1, N_NODES, 64);
  node_agg_kernel<HID><<<gAgg, 256, 0, stream>>>(rowptr, csr_src, el, er, featl, h);
  fill_f32<<<1, 128, 0, stream>>>(stats, 0.f, 128);
  bn_stats_kernel<<<512, 256, 0, stream>>>(h, stats, N_NODES);
  bn_finalize_kernel<<<1, 64, 0, stream>>>(stats, N_NODES);
  bn_apply_kernel<<<g64, B, 0, stream>>>(h, stats, g1, be1, N_NODES);

  // ================= layer 2 =================
  gemm_tiled<64, 160, 8, true><<<gGemm, 320, 0, stream>>>(h, W2, nullptr, featl, N_NODES);
  elr_kernel<<<gNH, B, 0, stream>>>(featl, al2, ar2, el, er, N_NODES, OUTC);
  gemm_tiled<64, 160, 8, false><<<gGemm, 320, 0, stream>>>(h, resW2, b2, out, N_NODES);
  node_agg_kernel<OUTC><<<gAgg, 256, 0, stream>>>(rowptr, csr_src, el, er, featl, out);
}

// Round 7
// 915.482 us; speedup vs baseline: 28.6660x; 1.0950x over previous
//
#include <hip/hip_runtime.h>
#include <cstdint>

#define N_NODES 100000
#define N_EDGES 1600000
#define F_IN 128
#define HID 16
#define HEADS 4
#define OUTC 40
#define NEG_SLOPE 0.2f
#define BN_EPS 1e-5f

// bucketed CSR build: bucket = dst >> 7 (128 nodes per bucket)
#define NBUCK ((N_NODES + 127) / 128)        // 782
#define SC_EDGES 16384                        // edges per bucket_scatter block

static inline int cdiv(int a, int b){ return (a + b - 1) / b; }

__device__ __forceinline__ float bf2f(unsigned short u){
  union { unsigned u32; float f; } v; v.u32 = ((unsigned)u) << 16; return v.f;
}
__device__ __forceinline__ unsigned short f2bf(float x){
  union { float f; unsigned u; } v; v.f = x;
  unsigned r = v.u + 0x7FFFu + ((v.u >> 16) & 1u);
  return (unsigned short)(r >> 16);
}

__global__ void fill_f32(float* p, float v, int n){
  int i = blockIdx.x * blockDim.x + threadIdx.x;
  if (i < n) p[i] = v;
}
__global__ void fill_i32(int* p, int v, int n){
  int i = blockIdx.x * blockDim.x + threadIdx.x;
  if (i < n) p[i] = v;
}

// ---------------- tiled register-blocked GEMM ----------------
template<int K, int M, int RT, bool BF16OUT>
__global__ __launch_bounds__((M / 4) * RT) void gemm_tiled(
    const float* __restrict__ A, const float* __restrict__ W,
    const float* __restrict__ bias, void* __restrict__ Cv, int n)
{
  constexpr int CT = M / 4;
  constexpr int BT = CT * RT;
  constexpr int ROWS = 64;
  constexpr int RPT = ROWS / RT;
  constexpr int KP = K + 4;
  __shared__ float ash[ROWS * KP];
  __shared__ float wsh[K * M];

  const int t = threadIdx.x;
  const int row0 = blockIdx.x * ROWS;

  const float4* Wv = (const float4*)W;
  for (int q = t; q < K * M / 4; q += BT)
    *(float4*)&wsh[q * 4] = Wv[q];

  for (int q = t; q < ROWS * K / 4; q += BT){
    int r = q / (K / 4);
    int kq = q - r * (K / 4);
    int grow = row0 + r;
    float4 v = make_float4(0.f, 0.f, 0.f, 0.f);
    if (grow < n) v = *(const float4*)&A[grow * K + kq * 4];
    *(float4*)&ash[r * KP + kq * 4] = v;
  }
  __syncthreads();

  const int c = t % CT;
  const int rt = t / CT;
  const int r0 = rt * RPT;

  float4 bb = make_float4(0.f, 0.f, 0.f, 0.f);
  if (bias) bb = ((const float4*)bias)[c];
  float4 acc[RPT];
  #pragma unroll
  for (int r = 0; r < RPT; ++r) acc[r] = bb;

  for (int k0 = 0; k0 < K; k0 += 4){
    float4 w0 = *(const float4*)&wsh[(k0 + 0) * M + c * 4];
    float4 w1 = *(const float4*)&wsh[(k0 + 1) * M + c * 4];
    float4 w2 = *(const float4*)&wsh[(k0 + 2) * M + c * 4];
    float4 w3 = *(const float4*)&wsh[(k0 + 3) * M + c * 4];
    #pragma unroll
    for (int r = 0; r < RPT; ++r){
      float4 a = *(const float4*)&ash[(r0 + r) * KP + k0];
      acc[r].x += a.x * w0.x + a.y * w1.x + a.z * w2.x + a.w * w3.x;
      acc[r].y += a.x * w0.y + a.y * w1.y + a.z * w2.y + a.w * w3.y;
      acc[r].z += a.x * w0.z + a.y * w1.z + a.z * w2.z + a.w * w3.z;
      acc[r].w += a.x * w0.w + a.y * w1.w + a.z * w2.w + a.w * w3.w;
    }
  }

  #pragma unroll
  for (int r = 0; r < RPT; ++r){
    int row = row0 + r0 + r;
    if (row < n){
      if (BF16OUT){
        ushort4 o;
        o.x = f2bf(acc[r].x); o.y = f2bf(acc[r].y);
        o.z = f2bf(acc[r].z); o.w = f2bf(acc[r].w);
        *(ushort4*)&((unsigned short*)Cv)[row * M + c * 4] = o;
      } else {
        *(float4*)&((float*)Cv)[row * M + c * 4] = acc[r];
      }
    }
  }
}

// el[n,h] = sum_d featl[n,h,d]*al[h,d]; er likewise (featl is bf16)
__global__ void elr_kernel(const unsigned short* __restrict__ featl,
                           const float* __restrict__ al, const float* __restrict__ ar,
                           float* __restrict__ el, float* __restrict__ er,
                           int n, int D){
  int idx = blockIdx.x * blockDim.x + threadIdx.x;
  if (idx >= n * HEADS) return;
  int h = idx & (HEADS - 1);
  const unsigned short* f = featl + (idx >> 2) * (HEADS * D) + h * D;
  float sl = 0.f, sr = 0.f;
  for (int d = 0; d < D; ++d){
    float v = bf2f(f[d]);
    sl += v * al[h * D + d];
    sr += v * ar[h * D + d];
  }
  el[idx] = sl;
  er[idx] = sr;
}

__global__ void residual2_kernel(float* __restrict__ hh, const float* __restrict__ b, int n, int F){
  int idx = blockIdx.x * blockDim.x + threadIdx.x;
  if (idx >= n * F) return;
  int f = idx % F;
  hh[idx] = 2.f * hh[idx] + b[f];
}

// ---------------- bucketed CSR build ----------------
// 1) global bucket counts via per-block LDS histograms
__global__ __launch_bounds__(256) void bucket_count(const int* __restrict__ dst,
                                                    int* __restrict__ gcount){
  __shared__ int lc[NBUCK];
  int t = threadIdx.x;
  for (int i = t; i < NBUCK; i += 256) lc[i] = 0;
  __syncthreads();
  for (int i = blockIdx.x * 256 + t; i < N_EDGES; i += gridDim.x * 256)
    atomicAdd(&lc[dst[i] >> 7], 1);
  __syncthreads();
  for (int i = t; i < NBUCK; i += 256)
    if (lc[i]) atomicAdd(&gcount[i], lc[i]);
}

// 2) exclusive scan of NBUCK counts (one block)
__global__ __launch_bounds__(1024) void bucket_scan(const int* __restrict__ gcount,
                                                    int* __restrict__ bbase,
                                                    int* __restrict__ gcursor){
  __shared__ int s[1024];
  int t = threadIdx.x;
  int v = (t < NBUCK) ? gcount[t] : 0;
  s[t] = v;
  __syncthreads();
  for (int off = 1; off < 1024; off <<= 1){
    int u = (t >= off) ? s[t - off] : 0;
    __syncthreads();
    s[t] += u;
    __syncthreads();
  }
  if (t < NBUCK){ bbase[t] = s[t] - v; gcursor[t] = s[t] - v; }
  if (t == NBUCK - 1) bbase[NBUCK] = s[t];
}

// 3) scatter (src,dst) pairs into bucket regions; chunk-reserved per block
__global__ __launch_bounds__(256) void bucket_scatter(const int* __restrict__ src,
                                                      const int* __restrict__ dst,
                                                      int* __restrict__ gcursor,
                                                      int2* __restrict__ pairs){
  __shared__ int lc[NBUCK];
  __shared__ int lp[NBUCK];
  int t = threadIdx.x;
  int e0 = blockIdx.x * SC_EDGES;
  int e1 = min(e0 + SC_EDGES, N_EDGES);
  for (int i = t; i < NBUCK; i += 256) lc[i] = 0;
  __syncthreads();
  for (int i = e0 + t; i < e1; i += 256)
    atomicAdd(&lc[dst[i] >> 7], 1);
  __syncthreads();
  for (int i = t; i < NBUCK; i += 256){
    int c = lc[i];
    lp[i] = c ? atomicAdd(&gcursor[i], c) : 0;
  }
  __syncthreads();
  for (int i = e0 + t; i < e1; i += 256){
    int d = dst[i];
    int pos = atomicAdd(&lp[d >> 7], 1);
    pairs[pos] = make_int2(src[i], d);
  }
}

// 4) per-bucket local counting sort -> rowptr + csr_src (one block per bucket)
__global__ __launch_bounds__(256) void bucket_build(const int2* __restrict__ pairs,
                                                    const int* __restrict__ bbase,
                                                    int* __restrict__ rowptr,
                                                    int* __restrict__ csr_src){
  __shared__ int lh[128];
  __shared__ int ls[128];
  int b = blockIdx.x;
  int t = threadIdx.x;
  int s0 = bbase[b], s1 = bbase[b + 1];
  if (t < 128) lh[t] = 0;
  __syncthreads();
  for (int i = s0 + t; i < s1; i += 256)
    atomicAdd(&lh[pairs[i].y & 127], 1);
  __syncthreads();
  if (t < 128) ls[t] = lh[t];
  __syncthreads();
  for (int off = 1; off < 128; off <<= 1){
    int u = (t < 128 && t >= off) ? ls[t - off] : 0;
    __syncthreads();
    if (t < 128) ls[t] += u;
    __syncthreads();
  }
  if (t < 128){
    int ex = s0 + ls[t] - lh[t];     // exclusive position
    int node = (b << 7) + t;
    if (node < N_NODES) rowptr[node] = ex;
    lh[t] = ex;                       // reuse as cursor
  }
  if (b == NBUCK - 1 && t == 0) rowptr[N_NODES] = N_EDGES;
  __syncthreads();
  for (int i = s0 + t; i < s1; i += 256){
    int2 p = pairs[i];
    int pos = atomicAdd(&lh[p.y & 127], 1);
    csr_src[pos] = p.x;
  }
}

// ---------------- per-node softmax + aggregation ----------------
__device__ __forceinline__ float leaky(float x){ return x >= 0.f ? x : NEG_SLOPE * x; }
__device__ __forceinline__ float sel4(float4 v, int h){
  float r = v.x;
  r = (h == 1) ? v.y : r;
  r = (h == 2) ? v.z : r;
  r = (h == 3) ? v.w : r;
  return r;
}

template<int D>
__global__ __launch_bounds__(256) void node_agg_kernel(
    const int* __restrict__ rowptr, const int* __restrict__ csr_src,
    const float* __restrict__ el, const float* __restrict__ er,
    const unsigned short* __restrict__ featl, float* __restrict__ io)
{
  constexpr int F = HEADS * D;
  __shared__ float alds[4][64][4];   // per-edge alpha (4 heads)
  __shared__ int   slds[4][64];      // per-edge src index
  int wid = threadIdx.x >> 6;
  int lane = threadIdx.x & 63;
  int node = blockIdx.x * 4 + wid;
  if (node >= N_NODES) return;
  int start = rowptr[node], end = rowptr[node + 1];
  int cnt = end - start;
  float4 erd = *(const float4*)(er + 4 * node);
  bool fast = (cnt <= 64);

  float4 mh, ih;
  if (fast){
    int sidx = 0;
    float x0 = -1e30f, x1 = -1e30f, x2 = -1e30f, x3 = -1e30f;
    if (lane < cnt){
      sidx = csr_src[start + lane];
      float4 e4 = *(const float4*)(el + 4 * sidx);
      x0 = leaky(e4.x + erd.x); x1 = leaky(e4.y + erd.y);
      x2 = leaky(e4.z + erd.z); x3 = leaky(e4.w + erd.w);
    }
    float m0 = x0, m1 = x1, m2 = x2, m3 = x3;
    #pragma unroll
    for (int off = 32; off; off >>= 1){
      m0 = fmaxf(m0, __shfl_xor(m0, off, 64));
      m1 = fmaxf(m1, __shfl_xor(m1, off, 64));
      m2 = fmaxf(m2, __shfl_xor(m2, off, 64));
      m3 = fmaxf(m3, __shfl_xor(m3, off, 64));
    }
    float e0 = 0.f, e1 = 0.f, e2 = 0.f, e3 = 0.f;
    if (lane < cnt){
      e0 = __expf(x0 - m0); e1 = __expf(x1 - m1);
      e2 = __expf(x2 - m2); e3 = __expf(x3 - m3);
    }
    float s0 = e0, s1 = e1, s2 = e2, s3 = e3;
    #pragma unroll
    for (int off = 32; off; off >>= 1){
      s0 += __shfl_xor(s0, off, 64);
      s1 += __shfl_xor(s1, off, 64);
      s2 += __shfl_xor(s2, off, 64);
      s3 += __shfl_xor(s3, off, 64);
    }
    ih = make_float4(1.f / fmaxf(s0, 1e-16f), 1.f / fmaxf(s1, 1e-16f),
                     1.f / fmaxf(s2, 1e-16f), 1.f / fmaxf(s3, 1e-16f));
    if (lane < cnt){
      slds[wid][lane] = sidx;
      float4 av = make_float4(e0 * ih.x, e1 * ih.y, e2 * ih.z, e3 * ih.w);
      *(float4*)&alds[wid][lane][0] = av;
    }
    // same-wave LDS write->read: DS ops of a wave complete in order; no barrier.
  } else {
    float m0 = -1e30f, m1 = -1e30f, m2 = -1e30f, m3 = -1e30f;
    for (int i = start + lane; i < end; i += 64){
      int s = csr_src[i];
      float4 e4 = *(const float4*)(el + 4 * s);
      m0 = fmaxf(m0, leaky(e4.x + erd.x));
      m1 = fmaxf(m1, leaky(e4.y + erd.y));
      m2 = fmaxf(m2, leaky(e4.z + erd.z));
      m3 = fmaxf(m3, leaky(e4.w + erd.w));
    }
    #pragma unroll
    for (int off = 32; off; off >>= 1){
      m0 = fmaxf(m0, __shfl_xor(m0, off, 64));
      m1 = fmaxf(m1, __shfl_xor(m1, off, 64));
      m2 = fmaxf(m2, __shfl_xor(m2, off, 64));
      m3 = fmaxf(m3, __shfl_xor(m3, off, 64));
    }
    float s0 = 0.f, s1 = 0.f, s2 = 0.f, s3 = 0.f;
    for (int i = start + lane; i < end; i += 64){
      int s = csr_src[i];
      float4 e4 = *(const float4*)(el + 4 * s);
      s0 += __expf(leaky(e4.x + erd.x) - m0);
      s1 += __expf(leaky(e4.y + erd.y) - m1);
      s2 += __expf(leaky(e4.z + erd.z) - m2);
      s3 += __expf(leaky(e4.w + erd.w) - m3);
    }
    #pragma unroll
    for (int off = 32; off; off >>= 1){
      s0 += __shfl_xor(s0, off, 64);
      s1 += __shfl_xor(s1, off, 64);
      s2 += __shfl_xor(s2, off, 64);
      s3 += __shfl_xor(s3, off, 64);
    }
    mh = make_float4(m0, m1, m2, m3);
    ih = make_float4(1.f / fmaxf(s0, 1e-16f), 1.f / fmaxf(s1, 1e-16f),
                     1.f / fmaxf(s2, 1e-16f), 1.f / fmaxf(s3, 1e-16f));
  }

  const int f0 = lane;
  const int h0 = f0 / D;
  float acc0 = io[node * F + f0];
  const unsigned short* fb = featl + f0;

  if (D == 16){
    if (fast){
      const float* ap = &alds[wid][0][h0];
      const int* sp = &slds[wid][0];
      int j = 0;
      for (; j + 3 < cnt; j += 4){
        int sA = sp[j], sB = sp[j + 1], sC = sp[j + 2], sD = sp[j + 3];
        float aA = ap[4 * j], aB = ap[4 * (j + 1)], aC = ap[4 * (j + 2)], aD = ap[4 * (j + 3)];
        acc0 += aA * bf2f(fb[sA * F]);
        acc0 += aB * bf2f(fb[sB * F]);
        acc0 += aC * bf2f(fb[sC * F]);
        acc0 += aD * bf2f(fb[sD * F]);
      }
      for (; j < cnt; ++j)
        acc0 += ap[4 * j] * bf2f(fb[sp[j] * F]);
    } else {
      const float er0 = sel4(erd, h0), mm0 = sel4(mh, h0), ii0 = sel4(ih, h0);
      for (int i = start; i < end; ++i){
        int s = csr_src[i];
        float4 e4 = *(const float4*)(el + 4 * s);
        acc0 += __expf(leaky(sel4(e4, h0) + er0) - mm0) * ii0 * bf2f(fb[s * F]);
      }
    }
    io[node * F + f0] = acc0;
  } else {
    const int h1 = (lane + 64) / D;
    const int h2 = 3;
    float acc1 = io[node * F + lane + 64];
    float acc2 = (lane < F - 128) ? io[node * F + lane + 128] : 0.f;
    if (fast){
      const float* ab = &alds[wid][0][0];
      const int* sp = &slds[wid][0];
      int j = 0;
      for (; j + 1 < cnt; j += 2){
        int sA = sp[j], sB = sp[j + 1];
        float aA0 = ab[4 * j + h0], aA1 = ab[4 * j + h1], aA2 = ab[4 * j + h2];
        float aB0 = ab[4 * (j + 1) + h0], aB1 = ab[4 * (j + 1) + h1], aB2 = ab[4 * (j + 1) + h2];
        acc0 += aA0 * bf2f(fb[sA * F]);
        acc1 += aA1 * bf2f(fb[sA * F + 64]);
        acc0 += aB0 * bf2f(fb[sB * F]);
        acc1 += aB1 * bf2f(fb[sB * F + 64]);
        if (lane < F - 128){
          acc2 += aA2 * bf2f(fb[sA * F + 128]);
          acc2 += aB2 * bf2f(fb[sB * F + 128]);
        }
      }
      for (; j < cnt; ++j){
        int s = sp[j];
        acc0 += ab[4 * j + h0] * bf2f(fb[s * F]);
        acc1 += ab[4 * j + h1] * bf2f(fb[s * F + 64]);
        if (lane < F - 128) acc2 += ab[4 * j + h2] * bf2f(fb[s * F + 128]);
      }
    } else {
      const float er0 = sel4(erd, h0), mm0 = sel4(mh, h0), ii0 = sel4(ih, h0);
      const float er1 = sel4(erd, h1), mm1 = sel4(mh, h1), ii1 = sel4(ih, h1);
      const float er2 = sel4(erd, h2), mm2 = sel4(mh, h2), ii2 = sel4(ih, h2);
      for (int i = start; i < end; ++i){
        int s = csr_src[i];
        float4 e4 = *(const float4*)(el + 4 * s);
        acc0 += __expf(leaky(sel4(e4, h0) + er0) - mm0) * ii0 * bf2f(fb[s * F]);
        acc1 += __expf(leaky(sel4(e4, h1) + er1) - mm1) * ii1 * bf2f(fb[s * F + 64]);
        if (lane < F - 128)
          acc2 += __expf(leaky(sel4(e4, h2) + er2) - mm2) * ii2 * bf2f(fb[s * F + 128]);
      }
    }
    io[node * F + f0] = acc0;
    io[node * F + lane + 64] = acc1;
    if (lane < F - 128) io[node * F + lane + 128] = acc2;
  }
}

// ---------------- BatchNorm ----------------
__global__ void bn_stats_kernel(const float* __restrict__ x, float* __restrict__ sums, int n){
  __shared__ float s[512];
  int tid = threadIdx.x;
  int f = tid & 63, g = tid >> 6;
  float sm = 0.f, sq = 0.f;
  for (int r = blockIdx.x * 4 + g; r < n; r += gridDim.x * 4){
    float v = x[r * 64 + f];
    sm += v; sq += v * v;
  }
  s[tid] = sm; s[256 + tid] = sq;
  __syncthreads();
  if (g == 0){
    float a = s[f] + s[64 + f] + s[128 + f] + s[192 + f];
    float b = s[256 + f] + s[320 + f] + s[384 + f] + s[448 + f];
    atomicAdd(&sums[f], a);
    atomicAdd(&sums[64 + f], b);
  }
}

__global__ void bn_finalize_kernel(float* __restrict__ stats, int n){
  int f = threadIdx.x;
  if (f < 64){
    float mu = stats[f] / n;
    float var = stats[64 + f] / n - mu * mu;
    stats[128 + f] = mu;
    stats[192 + f] = rsqrtf(var + BN_EPS);
  }
}

__global__ void bn_apply_kernel(float* __restrict__ x, const float* __restrict__ stats,
                                const float* __restrict__ gamma, const float* __restrict__ beta,
                                int n){
  int idx = blockIdx.x * blockDim.x + threadIdx.x;
  if (idx >= n * 64) return;
  int f = idx & 63;
  float v = (x[idx] - stats[128 + f]) * stats[192 + f] * gamma[f] + beta[f];
  x[idx] = v > 0.f ? v : 0.f;
}

extern "C" void kernel_launch(void* const* d_in, const int* in_sizes, int n_in,
                              void* d_out, int out_size, void* d_ws, size_t ws_size,
                              hipStream_t stream){
  const float* feat  = (const float*)d_in[0];
  const int*   src   = (const int*)d_in[1];
  const int*   dst   = (const int*)d_in[2];
  const float* W0    = (const float*)d_in[3];
  const float* al0   = (const float*)d_in[4];
  const float* ar0   = (const float*)d_in[5];
  const float* b0    = (const float*)d_in[6];
  const float* resW0 = (const float*)d_in[7];
  const float* g0    = (const float*)d_in[8];
  const float* be0   = (const float*)d_in[9];
  const float* W1    = (const float*)d_in[10];
  const float* al1   = (const float*)d_in[11];
  const float* ar1   = (const float*)d_in[12];
  const float* b1    = (const float*)d_in[13];
  const float* g1    = (const float*)d_in[14];
  const float* be1   = (const float*)d_in[15];
  const float* W2    = (const float*)d_in[16];
  const float* al2   = (const float*)d_in[17];
  const float* ar2   = (const float*)d_in[18];
  const float* b2    = (const float*)d_in[19];
  const float* resW2 = (const float*)d_in[20];
  float* out = (float*)d_out;

  // ws layout: pairs first (8B-aligned), then the rest
  int2* pairs  = (int2*)d_ws;                             // E int2
  unsigned short* featl = (unsigned short*)(pairs + N_EDGES); // N*160 bf16
  float* h     = (float*)(featl + N_NODES * 160);         // N*64 f32
  float* el    = h + N_NODES * 64;                        // N*4
  float* er    = el + N_NODES * 4;                        // N*4
  float* stats = er + N_NODES * 4;                        // 256
  int* rowptr  = (int*)(stats + 256);                     // N+1
  int* gcount  = rowptr + (N_NODES + 1);                  // NBUCK
  int* bbase   = gcount + NBUCK;                          // NBUCK+1
  int* gcursor = bbase + NBUCK + 1;                       // NBUCK
  int* csr_src = gcursor + NBUCK;                         // E

  const int B = 256;
  const int gNH  = cdiv(N_NODES * HEADS, B);
  const int g64  = cdiv(N_NODES * 64, B);
  const int gAgg = cdiv(N_NODES, 4);
  const int gGemm = cdiv(N_NODES, 64);

  // ---------- bucketed CSR build (reused by all 3 layers) ----------
  fill_i32<<<cdiv(NBUCK, B), B, 0, stream>>>(gcount, 0, NBUCK);
  bucket_count<<<256, B, 0, stream>>>(dst, gcount);
  bucket_scan<<<1, 1024, 0, stream>>>(gcount, bbase, gcursor);
  bucket_scatter<<<cdiv(N_EDGES, SC_EDGES), B, 0, stream>>>(src, dst, gcursor, pairs);
  bucket_build<<<NBUCK, B, 0, stream>>>(pairs, bbase, rowptr, csr_src);

  // ================= layer 0 =================
  gemm_tiled<128, 64, 16, true><<<gGemm, 256, 0, stream>>>(feat, W0, nullptr, featl, N_NODES);
  elr_kernel<<<gNH, B, 0, stream>>>(featl, al0, ar0, el, er, N_NODES, HID);
  gemm_tiled<128, 64, 16, false><<<gGemm, 256, 0, stream>>>(feat, resW0, b0, h, N_NODES);
  node_agg_kernel<HID><<<gAgg, 256, 0, stream>>>(rowptr, csr_src, el, er, featl, h);
  fill_f32<<<1, 128, 0, stream>>>(stats, 0.f, 128);
  bn_stats_kernel<<<512, 256, 0, stream>>>(h, stats, N_NODES);
  bn_finalize_kernel<<<1, 64, 0, stream>>>(stats, N_NODES);
  bn_apply_kernel<<<g64, B, 0, stream>>>(h, stats, g0, be0, N_NODES);

  // ================= layer 1 =================
  gemm_tiled<64, 64, 16, true><<<gGemm, 256, 0, stream>>>(h, W1, nullptr, featl, N_NODES);
  elr_kernel<<<gNH, B, 0, stream>>>(featl, al1, ar1, el, er, N_NODES, HID);
  residual2_kernel<<<g64, B, 0, stream>>>(h, b1, N_NODES, 64);
  node_agg_kernel<HID><<<gAgg, 256, 0, stream>>>(rowptr, csr_src, el, er, featl, h);
  fill_f32<<<1, 128, 0, stream>>>(stats, 0.f, 128);
  bn_stats_kernel<<<512, 256, 0, stream>>>(h, stats, N_NODES);
  bn_finalize_kernel<<<1, 64, 0, stream>>>(stats, N_NODES);
  bn_apply_kernel<<<g64, B, 0, stream>>>(h, stats, g1, be1, N_NODES);

  // ================= layer 2 =================
  gemm_tiled<64, 160, 8, true><<<gGemm, 320, 0, stream>>>(h, W2, nullptr, featl, N_NODES);
  elr_kernel<<<gNH, B, 0, stream>>>(featl, al2, ar2, el, er, N_NODES, OUTC);
  gemm_tiled<64, 160, 8, false><<<gGemm, 320, 0, stream>>>(h, resW2, b2, out, N_NODES);
  node_agg_kernel<OUTC><<<gAgg, 256, 0, stream>>>(rowptr, csr_src, el, er, featl, out);
}